// Round 11
// baseline (808.559 us; speedup 1.0000x reference)
//
#include <hip/hip_runtime.h>
#include <math.h>

#define N_ROWS 16384
#define VOCAB  8192
#define EMB    256

// ---- MFMA path tiling ----
#define BM 128
#define BV 128
#define BK 64                      // halfs per staged cb K-chunk (2 MFMA k-steps)
#define VSPLIT 8                   // grid (128, 8)
#define VRANGE (VOCAB / VSPLIT)    // 1024
#define NVT    (VRANGE / BV)       // 8
#define TAU 0.15f                  // >= 2*max|dist err| over 1.3e8 pairs (fp16 inputs)

typedef _Float16 half8 __attribute__((ext_vector_type(8)));
typedef _Float16 half4 __attribute__((ext_vector_type(4)));
typedef float floatx4 __attribute__((ext_vector_type(4)));

// async global->LDS DMA, 16 B/lane; LDS dest = wave-uniform base + lane*16
__device__ __forceinline__ void load_lds16(const _Float16* g, _Float16* l) {
    __builtin_amdgcn_global_load_lds(
        (const __attribute__((address_space(1))) void*)g,
        (__attribute__((address_space(3))) void*)l, 16, 0, 0);
}

// ---------------------------------------------------------------------------
// PREP (1 dispatch: esq + fp16 convert + output/scratch init).
// ---------------------------------------------------------------------------
__global__ void prep_kernel(const float* __restrict__ z, const float* __restrict__ cb,
                            _Float16* __restrict__ zh, _Float16* __restrict__ ch,
                            float* __restrict__ esq, float* __restrict__ cnt,
                            unsigned long long* __restrict__ rkey,
                            int* __restrict__ flagcnt) {
    const int b = blockIdx.x, t = threadIdx.x;
    if (b < VOCAB / 4) {
        const int row  = b * 4 + (t >> 6);
        const int lane = t & 63;
        const float4 f = *(const float4*)(cb + (size_t)row * EMB + lane * 4);
        half4 h;
        h.x = (_Float16)f.x; h.y = (_Float16)f.y; h.z = (_Float16)f.z; h.w = (_Float16)f.w;
        *(half4*)(ch + (size_t)row * EMB + lane * 4) = h;
        float s = f.x * f.x + f.y * f.y + f.z * f.z + f.w * f.w;
        #pragma unroll
        for (int off = 32; off > 0; off >>= 1) s += __shfl_down(s, off, 64);
        if (lane == 0) esq[row] = s;
        if (t < 4) cnt[b * 4 + t] = 0.0f;
        if (t >= 8 && t < 16) rkey[b * 8 + (t - 8)] = ~0ull;
        if (b == 0 && t == 4) *flagcnt = 0;
    } else {
        const size_t idx4 = (size_t)(b - VOCAB / 4) * 256 + t;
        const float4 f = *(const float4*)(z + idx4 * 4);
        half4 h;
        h.x = (_Float16)f.x; h.y = (_Float16)f.y; h.z = (_Float16)f.z; h.w = (_Float16)f.w;
        *(half4*)(zh + idx4 * 4) = h;
    }
}

// ---------------------------------------------------------------------------
// MFMA dist kernel v9: z tile RESIDENT in LDS (staged once; v8 re-staged it
// every vt = 8x wasted DMA). z layout: [row][32 chunks of 8 halfs], chunk c
// stored at slot c ^ (r&31) -> frag reads tile all banks 2-way (free).
// cb tiles per kt as v8 (BK=64, chunk ^ (r&7) swizzle). LDS 64+16=80 KB
// -> 2 blocks/CU. acc init = -0.5*esq[col]; per-row ARGMAX of acc.
// ---------------------------------------------------------------------------
__global__ __launch_bounds__(256, 2)
void mfma_dist_kernel(const _Float16* __restrict__ zh, const _Float16* __restrict__ ch,
                      const float* __restrict__ esq,
                      float* __restrict__ pd1, int* __restrict__ pi1,
                      float* __restrict__ pd2) {
    __shared__ _Float16 zl[BM * 256];  // 64 KB, resident z tile (swizzled)
    __shared__ _Float16 cs[BV * BK];   // 16 KB, per-kt cb tile (v8 swizzle)
    float* sc_d1 = (float*)zl;         // end-phase alias (3 KB; z dead by then)
    float* sc_d2 = sc_d1 + BM * 2;
    int*   sc_i1 = (int*)(sc_d2 + BM * 2);

    const int row0  = blockIdx.x * BM;
    const int vbase = blockIdx.y * VRANGE;

    const int tid  = threadIdx.x;
    const int w    = tid >> 6;
    const int lane = tid & 63;
    const int lr   = lane & 15;
    const int quad = lane >> 4;
    const int mh   = (w >> 1) * 64;
    const int vh   = (w & 1) * 64;

    // ---- stage z ONCE: wave w covers rows [w*32, w*32+32), 16 DMA instrs ----
    {
        const int rl = lane >> 5;             // 0..1
        const int sc = lane & 31;             // dest slot within row-pair
        #pragma unroll
        for (int i = 0; i < 16; ++i) {
            const int r = w * 32 + i * 2 + rl;
            const int c = sc ^ (i * 2 + rl);  // source chunk (slot ^ (r&31))
            load_lds16(zh + (size_t)(row0 + r) * EMB + c * 8,
                       zl + (size_t)(w * 1024 + i * 64) * 8);
        }
    }

    // z fragment row offsets (halfs): row mh+i*16+lr
    int rowOffZ[4];
    #pragma unroll
    for (int i = 0; i < 4; ++i) rowOffZ[i] = (mh + i * 16 + lr) * 256;

    // cb fragment addressing (v8)
    const int q7 = quad ^ (lr & 7);
    const int offA0 = q7 * 8;
    const int offA1 = (4 ^ q7) * 8;
    int rB[4];
    #pragma unroll
    for (int j = 0; j < 4; ++j) rB[j] = (vh + j * 16 + lr) * BK;

    // cb staging addressing (v8)
    const int schunk = (lane & 7) ^ (lane >> 3);

    float m1[16], m2[16]; int i1[16];
    #pragma unroll
    for (int t = 0; t < 16; ++t) { m1[t] = -INFINITY; m2[t] = -INFINITY; i1[t] = 0; }

    float ev[4];
    #pragma unroll
    for (int j = 0; j < 4; ++j) ev[j] = esq[vbase + vh + j * 16 + lr];

    __syncthreads();   // z DMA drained (vmcnt(0) before barrier)

    for (int vt = 0; vt < NVT; ++vt) {
        const int v0 = vbase + vt * BV;
        const _Float16* csrc = ch + (size_t)(v0 + w * 32 + (lane >> 3)) * EMB + schunk * 8;

        floatx4 acc[4][4];
        #pragma unroll
        for (int j = 0; j < 4; ++j) {
            const float e2 = -0.5f * ev[j];
            #pragma unroll
            for (int i = 0; i < 4; ++i) acc[i][j] = (floatx4)e2;
        }
        float evn[4];
        {
            const int vtn = (vt + 1 < NVT) ? vt + 1 : vt;
            #pragma unroll
            for (int j = 0; j < 4; ++j) evn[j] = esq[vbase + vtn * BV + vh + j * 16 + lr];
        }

        #pragma unroll 1
        for (int kt = 0; kt < EMB / BK; ++kt) {
            const int ko = kt * BK;
            #pragma unroll
            for (int q = 0; q < 4; ++q)
                load_lds16(csrc + (size_t)q * 8 * EMB + ko, &cs[w * 2048 + q * 512]);
            __syncthreads();

            #pragma unroll
            for (int s = 0; s < 2; ++s) {
                const int ks = kt * 2 + s;                    // global kstep 0..7
                const int cE = (((ks << 2) | quad) ^ lr) << 3; // z chunk offset, even i
                const int cO = cE ^ 128;                       // odd i (bit4 of slot)
                half8 a[4];
                a[0] = *(const half8*)&zl[rowOffZ[0] + cE];
                a[1] = *(const half8*)&zl[rowOffZ[1] + cO];
                a[2] = *(const half8*)&zl[rowOffZ[2] + cE];
                a[3] = *(const half8*)&zl[rowOffZ[3] + cO];
                const int off = s ? offA1 : offA0;
                #pragma unroll
                for (int j = 0; j < 4; ++j) {
                    const half8 b = *(const half8*)&cs[rB[j] + off];
                    #pragma unroll
                    for (int i = 0; i < 4; ++i)
                        acc[i][j] = __builtin_amdgcn_mfma_f32_16x16x32_f16(a[i], b, acc[i][j], 0, 0, 0);
                }
            }
            __syncthreads();
        }

        // epilogue: register-only top-2 (argmax acc)
        int vj[4];
        #pragma unroll
        for (int j = 0; j < 4; ++j) vj[j] = v0 + vh + j * 16 + lr;
        #pragma unroll
        for (int i = 0; i < 4; ++i) {
            #pragma unroll
            for (int reg = 0; reg < 4; ++reg) {
                const int t = i * 4 + reg;
                #pragma unroll
                for (int j = 0; j < 4; ++j) {
                    const float a = acc[i][j][reg];
                    m2[t] = fmaxf(m2[t], fminf(a, m1[t]));
                    i1[t] = (a > m1[t]) ? vj[j] : i1[t];
                    m1[t] = fmaxf(m1[t], a);
                }
            }
        }
        #pragma unroll
        for (int j = 0; j < 4; ++j) ev[j] = evn[j];
    }

    // ONE cross-lane reduce: 16 lr-lanes (same quad) share each row
    #pragma unroll
    for (int t = 0; t < 16; ++t) {
        float a1 = m1[t], a2 = m2[t]; int ii = i1[t];
        #pragma unroll
        for (int off = 1; off < 16; off <<= 1) {
            const float o1 = __shfl_xor(a1, off, 64);
            const int   oi = __shfl_xor(ii, off, 64);
            const float o2 = __shfl_xor(a2, off, 64);
            if (o1 > a1) { a2 = fmaxf(a1, o2); a1 = o1; ii = oi; }
            else         { a2 = fmaxf(a2, o1); }
        }
        m1[t] = a1; m2[t] = a2; i1[t] = ii;
    }
    // all waves past the last kt barrier -> z reads done; alias safe
    if (lr == 0) {
        #pragma unroll
        for (int t = 0; t < 16; ++t) {
            const int r = mh + (t >> 2) * 16 + quad * 4 + (t & 3);
            sc_d1[r * 2 + (w & 1)] = m1[t];
            sc_d2[r * 2 + (w & 1)] = m2[t];
            sc_i1[r * 2 + (w & 1)] = i1[t];
        }
    }
    __syncthreads();
    if (tid < BM) {
        float a1 = sc_d1[tid * 2], a2 = sc_d2[tid * 2]; int ii = sc_i1[tid * 2];
        const float o1 = sc_d1[tid * 2 + 1], o2 = sc_d2[tid * 2 + 1];
        const int   oi = sc_i1[tid * 2 + 1];
        if (o1 > a1) { a2 = fmaxf(a1, o2); a1 = o1; ii = oi; }
        else         { a2 = fmaxf(a2, o1); }
        const size_t o = (size_t)blockIdx.y * N_ROWS + row0 + tid;
        pd1[o] = -2.0f * a1; pi1[o] = ii; pd2[o] = -2.0f * a2;
    }
}

// ---------------------------------------------------------------------------
// Combine: merge VSPLIT top-2 partials; margin >= TAU -> commit, else flag.
// ---------------------------------------------------------------------------
__global__ void combine_kernel(const float* __restrict__ pd1, const int* __restrict__ pi1,
                               const float* __restrict__ pd2,
                               const float* __restrict__ cb,
                               float* __restrict__ tokens, float* __restrict__ zq,
                               float* __restrict__ cnt,
                               int* __restrict__ flagcnt, int* __restrict__ flaglist) {
    const int wave = threadIdx.x >> 6;
    const int lane = threadIdx.x & 63;
    const int row  = blockIdx.x * 4 + wave;

    float d1 = INFINITY, d2 = INFINITY; int i1 = 0;
    #pragma unroll
    for (int s = 0; s < VSPLIT; ++s) {
        const size_t o = (size_t)s * N_ROWS + row;
        const float od1 = pd1[o], od2 = pd2[o]; const int oi1 = pi1[o];
        if (od1 < d1) { d2 = fminf(d1, od2); d1 = od1; i1 = oi1; }
        else          { d2 = fminf(d2, od1); }
    }
    if ((d2 - d1) < TAU) {
        if (lane == 0) {
            const int pos = atomicAdd(flagcnt, 1);
            flaglist[pos] = row;
        }
        return;   // rescue writes this row
    }
    if (lane == 0) {
        tokens[row] = (float)i1;
        atomicAdd(&cnt[i1], 1.0f);
    }
    const float4 v = *(const float4*)(cb + (size_t)i1 * EMB + lane * 4);
    *(float4*)(zq + (size_t)row * EMB + lane * 4) = v;
}

// ---------------------------------------------------------------------------
// Rescue v5: exact fp32 argmin. Round 10 showed rescue is L2-BW bound
// (n x 8 MB codebook re-read = 4 GB). Fix: job = (row-QUAD, 64-code chunk)
// per wave -> each cb read serves 4 rows (L2 bytes / 4). 4 lanes/code x 16
// codes; z slices broadcast-coalesced. Duplicate rows (n%4 pad) are
// idempotent under atomicMin.
// ---------------------------------------------------------------------------
__global__ void rescue5_kernel(const int* __restrict__ flagcnt, const int* __restrict__ flaglist,
                               const float* __restrict__ z, const float* __restrict__ cb,
                               const float* __restrict__ esq,
                               unsigned long long* __restrict__ rkey) {
    const int tid  = threadIdx.x;
    const int w    = tid >> 6;
    const int lane = tid & 63;
    const int g    = lane >> 2;        // code group 0..15
    const int s    = lane & 3;         // sub-lane: dims k*16 + s*4
    const int n = *flagcnt;
    if (n == 0) return;
    const int nq = (n + 3) >> 2;       // row quads
    const int waveId = blockIdx.x * 4 + w;
    const int nwaves = gridDim.x * 4;
    const int njobs  = nq * 128;       // 128 chunks of 64 codes per row-quad
    for (int j = waveId; j < njobs; j += nwaves) {
        const int qt = j >> 7;
        const int c0 = (j & 127) * 64;
        int rows[4];
        #pragma unroll
        for (int r = 0; r < 4; ++r) {
            int f = qt * 4 + r; if (f >= n) f = n - 1;
            rows[r] = flaglist[f];
        }
        float p[4][4];                 // [gs][row]
        #pragma unroll
        for (int gs = 0; gs < 4; ++gs)
            #pragma unroll
            for (int r = 0; r < 4; ++r) p[gs][r] = 0.0f;
        #pragma unroll
        for (int kb = 0; kb < 4; ++kb) {
            float4 zv[4][4];           // [row][kk]
            #pragma unroll
            for (int r = 0; r < 4; ++r)
                #pragma unroll
                for (int kk = 0; kk < 4; ++kk)
                    zv[r][kk] = *(const float4*)(z + (size_t)rows[r] * EMB + (kb * 4 + kk) * 16 + s * 4);
            #pragma unroll
            for (int gs = 0; gs < 4; ++gs) {
                const float* cr = cb + (size_t)(c0 + gs * 16 + g) * EMB;
                #pragma unroll
                for (int kk = 0; kk < 4; ++kk) {
                    const float4 c4 = *(const float4*)(cr + (kb * 4 + kk) * 16 + s * 4);
                    #pragma unroll
                    for (int r = 0; r < 4; ++r)
                        p[gs][r] += zv[r][kk].x * c4.x + zv[r][kk].y * c4.y
                                  + zv[r][kk].z * c4.z + zv[r][kk].w * c4.w;
                }
            }
        }
        #pragma unroll
        for (int r = 0; r < 4; ++r) {
            float bd = INFINITY; int bv = 0;
            #pragma unroll
            for (int gs = 0; gs < 4; ++gs) {
                float pp = p[gs][r];
                pp += __shfl_xor(pp, 1, 64);
                pp += __shfl_xor(pp, 2, 64);   // 4 quad-lanes hold full dot
                const int v = c0 + gs * 16 + g;
                const float d = esq[v] - 2.0f * pp;
                if (d < bd) { bd = d; bv = v; } // gs ascending -> lowest tie idx
            }
            #pragma unroll
            for (int off = 4; off < 64; off <<= 1) {
                const float od = __shfl_xor(bd, off, 64);
                const int   ov = __shfl_xor(bv, off, 64);
                if (od < bd || (od == bd && ov < bv)) { bd = od; bv = ov; }
            }
            if (lane == 0) {
                unsigned int u = __float_as_uint(bd);
                u = (u & 0x80000000u) ? ~u : (u | 0x80000000u);
                atomicMin(rkey + rows[r], ((unsigned long long)u << 32) | (unsigned int)bv);
            }
        }
    }
}

// ---------------------------------------------------------------------------
// Rescue writer: separate dispatch (kernel boundary = visibility ordering).
// ---------------------------------------------------------------------------
__global__ void rescue_write_kernel(const int* __restrict__ flagcnt,
                                    const int* __restrict__ flaglist,
                                    const unsigned long long* __restrict__ rkey,
                                    const float* __restrict__ cb,
                                    float* __restrict__ tokens, float* __restrict__ zq,
                                    float* __restrict__ cnt) {
    const int w    = threadIdx.x >> 6;
    const int lane = threadIdx.x & 63;
    const int n = *flagcnt;
    for (int f = blockIdx.x * 4 + w; f < n; f += gridDim.x * 4) {
        const int row = flaglist[f];
        const int v = (int)(unsigned int)(rkey[row] & 0xFFFFFFFFull);
        if (lane == 0) {
            tokens[row] = (float)v;
            atomicAdd(&cnt[v], 1.0f);
        }
        const float4 c4 = *(const float4*)(cb + (size_t)v * EMB + lane * 4);
        *(float4*)(zq + (size_t)row * EMB + lane * 4) = c4;
    }
}

// ===========================================================================
// Fallback (round-3 fp32 path) if ws is too small.
// ===========================================================================
__global__ void esq_kernel(const float* __restrict__ cb, float* __restrict__ esq) {
    const int wave = threadIdx.x >> 6;
    const int lane = threadIdx.x & 63;
    const int row  = blockIdx.x * 4 + wave;
    const float4 v = *(const float4*)(cb + (size_t)row * EMB + lane * 4);
    float s = v.x * v.x + v.y * v.y + v.z * v.z + v.w * v.w;
    #pragma unroll
    for (int off = 32; off > 0; off >>= 1) s += __shfl_down(s, off, 64);
    if (lane == 0) esq[row] = s;
}

#define FLSTR 36
__global__ __launch_bounds__(256, 2)
void fb_dist_kernel(const float* __restrict__ z, const float* __restrict__ cb,
                    const float* __restrict__ esq,
                    float* __restrict__ pdist, int* __restrict__ pidx) {
    __shared__ float zs[BM][FLSTR];
    __shared__ float es[BV][FLSTR];
    __shared__ float rdist[16][16];
    __shared__ int   ridx [16][16];
    const int row0 = blockIdx.x * BM, vbase = blockIdx.y * VRANGE;
    const int tid = threadIdx.x, wave = tid >> 6, lane = tid & 63;
    const int wly = (lane >> 3) & 7, wlx = lane & 7;
    const int wbase = (wave >> 1) * 64, cbase = (wave & 1) * 64;
    const int arow = wbase + wly, bcol = cbase + wlx;
    const int rowSlot = (wave >> 1) * 8 + wly, colSlot = (wave & 1) * 8 + wlx;
    const int sc4 = tid & 7, sr0 = tid >> 3;
    float best[8]; int bidx[8];
    #pragma unroll
    for (int i = 0; i < 8; ++i) { best[i] = INFINITY; bidx[i] = 0; }
    for (int vt = 0; vt < NVT; ++vt) {
        const int v0 = vbase + vt * BV;
        float acc[8][8];
        #pragma unroll
        for (int i = 0; i < 8; ++i)
            #pragma unroll
            for (int j = 0; j < 8; ++j) acc[i][j] = 0.0f;
        #pragma unroll 1
        for (int kt = 0; kt < EMB / 32; ++kt) {
            #pragma unroll
            for (int t = 0; t < 4; ++t) {
                const int r = sr0 + 32 * t;
                *(float4*)&zs[r][sc4 * 4] = *(const float4*)(z  + (size_t)(row0 + r) * EMB + kt * 32 + sc4 * 4);
                *(float4*)&es[r][sc4 * 4] = *(const float4*)(cb + (size_t)(v0 + r) * EMB + kt * 32 + sc4 * 4);
            }
            __syncthreads();
            #pragma unroll 1
            for (int k0 = 0; k0 < 8; ++k0) {
                const int kk = k0 * 4;
                float a[8][4];
                #pragma unroll
                for (int i = 0; i < 8; ++i) {
                    const float4 a4 = *(const float4*)&zs[arow + 8 * i][kk];
                    a[i][0] = a4.x; a[i][1] = a4.y; a[i][2] = a4.z; a[i][3] = a4.w;
                }
                #pragma unroll
                for (int j = 0; j < 8; ++j) {
                    const float4 b4 = *(const float4*)&es[bcol + 8 * j][kk];
                    #pragma unroll
                    for (int i = 0; i < 8; ++i) {
                        acc[i][j] += a[i][0] * b4.x; acc[i][j] += a[i][1] * b4.y;
                        acc[i][j] += a[i][2] * b4.z; acc[i][j] += a[i][3] * b4.w;
                    }
                }
            }
            __syncthreads();
        }
        #pragma unroll
        for (int j = 0; j < 8; ++j) {
            const int v = v0 + bcol + 8 * j;
            const float evv = esq[v];
            #pragma unroll
            for (int i = 0; i < 8; ++i) {
                const float d = evv - 2.0f * acc[i][j];
                if (d < best[i]) { best[i] = d; bidx[i] = v; }
            }
        }
    }
    for (int i = 0; i < 8; ++i) {
        rdist[rowSlot][colSlot] = best[i];
        ridx [rowSlot][colSlot] = bidx[i];
        __syncthreads();
        if (colSlot == 0) {
            float bd = rdist[rowSlot][0]; int bi = ridx[rowSlot][0];
            #pragma unroll
            for (int t = 1; t < 16; ++t) {
                const float d = rdist[rowSlot][t]; const int ii = ridx[rowSlot][t];
                if (d < bd || (d == bd && ii < bi)) { bd = d; bi = ii; }
            }
            const int row = row0 + wbase + 8 * i + wly;
            pdist[(size_t)blockIdx.y * N_ROWS + row] = bd;
            pidx [(size_t)blockIdx.y * N_ROWS + row] = bi;
        }
        __syncthreads();
    }
}

__global__ void fb_combine_kernel(const float* __restrict__ pdist, const int* __restrict__ pidx,
                                  const float* __restrict__ cb,
                                  float* __restrict__ tokens, float* __restrict__ zq,
                                  float* __restrict__ cnt) {
    const int wave = threadIdx.x >> 6, lane = threadIdx.x & 63;
    const int row = blockIdx.x * 4 + wave;
    float bd = INFINITY; int bi = 0;
    #pragma unroll
    for (int s = 0; s < VSPLIT; ++s) {
        const float d = pdist[(size_t)s * N_ROWS + row];
        const int ii  = pidx [(size_t)s * N_ROWS + row];
        if (d < bd || (d == bd && ii < bi)) { bd = d; bi = ii; }
    }
    if (lane == 0) { tokens[row] = (float)bi; atomicAdd(&cnt[bi], 1.0f); }
    const float4 v = *(const float4*)(cb + (size_t)bi * EMB + lane * 4);
    *(float4*)(zq + (size_t)row * EMB + lane * 4) = v;
}

// ---------------------------------------------------------------------------
// d_out: [0,N) tokens | [N, N+N*EMB) zq | +VOCAB ref_count
// ws: zh | ch | esq | pd1|pd2|pi1 | rkey | flagcnt | flaglist  ~= 13.8 MB
// 5 dispatches: prep -> mfma_dist -> combine -> rescue5 -> rescue_write
// ---------------------------------------------------------------------------
extern "C" void kernel_launch(void* const* d_in, const int* in_sizes, int n_in,
                              void* d_out, int out_size, void* d_ws, size_t ws_size,
                              hipStream_t stream) {
    const float* z  = (const float*)d_in[0];
    const float* cb = (const float*)d_in[1];

    float* out    = (float*)d_out;
    float* tokens = out;
    float* zq     = out + N_ROWS;
    float* cnt    = out + N_ROWS + (size_t)N_ROWS * EMB;

    const size_t ZE = (size_t)N_ROWS * EMB, CE = (size_t)VOCAB * EMB, P = (size_t)VSPLIT * N_ROWS;
    const size_t NEED = (ZE + CE) * sizeof(_Float16) + VOCAB * 4
                      + 3 * P * 4 + (size_t)N_ROWS * 8 + 256 + N_ROWS * 4;

    if (ws_size >= NEED) {
        char* p = (char*)d_ws;
        _Float16* zh = (_Float16*)p;            p += ZE * 2;
        _Float16* ch = (_Float16*)p;            p += CE * 2;
        float* esq   = (float*)p;               p += VOCAB * 4;
        float* pd1   = (float*)p;               p += P * 4;
        float* pd2   = (float*)p;               p += P * 4;
        int*   pi1   = (int*)p;                 p += P * 4;
        unsigned long long* rkey = (unsigned long long*)p;  p += (size_t)N_ROWS * 8;
        int*   flagcnt = (int*)p;               p += 256;
        int*   flaglist = (int*)p;

        prep_kernel<<<VOCAB / 4 + (int)(ZE / 4 / 256), 256, 0, stream>>>(
            z, cb, zh, ch, esq, cnt, rkey, flagcnt);
        mfma_dist_kernel<<<dim3(N_ROWS / BM, VSPLIT), 256, 0, stream>>>(
            zh, ch, esq, pd1, pi1, pd2);
        combine_kernel<<<N_ROWS / 4, 256, 0, stream>>>(
            pd1, pi1, pd2, cb, tokens, zq, cnt, flagcnt, flaglist);
        rescue5_kernel<<<2048, 256, 0, stream>>>(flagcnt, flaglist, z, cb, esq, rkey);
        rescue_write_kernel<<<32, 256, 0, stream>>>(flagcnt, flaglist, rkey, cb, tokens, zq, cnt);
    } else {
        float* esq   = (float*)d_ws;
        float* pdist = esq + VOCAB;
        int*   pidx  = (int*)(pdist + P);
        hipMemsetAsync(cnt, 0, VOCAB * sizeof(float), stream);
        esq_kernel<<<VOCAB / 4, 256, 0, stream>>>(cb, esq);
        fb_dist_kernel<<<dim3(N_ROWS / BM, VSPLIT), 256, 0, stream>>>(z, cb, esq, pdist, pidx);
        fb_combine_kernel<<<N_ROWS / 4, 256, 0, stream>>>(pdist, pidx, cb, tokens, zq, cnt);
    }
}

// Round 12
// 519.266 us; speedup vs baseline: 1.5571x; 1.5571x over previous
//
#include <hip/hip_runtime.h>
#include <math.h>

#define N_ROWS 16384
#define VOCAB  8192
#define EMB    256

// ---- MFMA path tiling ----
#define BM 128
#define BV 128
#define BK 64                      // halfs per staged cb K-chunk (2 MFMA k-steps)
#define VSPLIT 8                   // grid (128, 8)
#define VRANGE (VOCAB / VSPLIT)    // 1024
#define NVT    (VRANGE / BV)       // 8
#define TAU 0.15f                  // >= 2*max|dist err| over 1.3e8 pairs (fp16 inputs)

typedef _Float16 half8 __attribute__((ext_vector_type(8)));
typedef _Float16 half4 __attribute__((ext_vector_type(4)));
typedef float floatx4 __attribute__((ext_vector_type(4)));

// async global->LDS DMA, 16 B/lane; LDS dest = wave-uniform base + lane*16
__device__ __forceinline__ void load_lds16(const _Float16* g, _Float16* l) {
    __builtin_amdgcn_global_load_lds(
        (const __attribute__((address_space(1))) void*)g,
        (__attribute__((address_space(3))) void*)l, 16, 0, 0);
}

// ---------------------------------------------------------------------------
// PREP (1 dispatch: esq + fp16 convert + output/scratch init).
// ---------------------------------------------------------------------------
__global__ void prep_kernel(const float* __restrict__ z, const float* __restrict__ cb,
                            _Float16* __restrict__ zh, _Float16* __restrict__ ch,
                            float* __restrict__ esq, float* __restrict__ cnt,
                            unsigned long long* __restrict__ rkey,
                            int* __restrict__ flagcnt) {
    const int b = blockIdx.x, t = threadIdx.x;
    if (b < VOCAB / 4) {
        const int row  = b * 4 + (t >> 6);
        const int lane = t & 63;
        const float4 f = *(const float4*)(cb + (size_t)row * EMB + lane * 4);
        half4 h;
        h.x = (_Float16)f.x; h.y = (_Float16)f.y; h.z = (_Float16)f.z; h.w = (_Float16)f.w;
        *(half4*)(ch + (size_t)row * EMB + lane * 4) = h;
        float s = f.x * f.x + f.y * f.y + f.z * f.z + f.w * f.w;
        #pragma unroll
        for (int off = 32; off > 0; off >>= 1) s += __shfl_down(s, off, 64);
        if (lane == 0) esq[row] = s;
        if (t < 4) cnt[b * 4 + t] = 0.0f;
        if (t >= 8 && t < 16) rkey[b * 8 + (t - 8)] = ~0ull;
        if (b == 0 && t == 4) *flagcnt = 0;
    } else {
        const size_t idx4 = (size_t)(b - VOCAB / 4) * 256 + t;
        const float4 f = *(const float4*)(z + idx4 * 4);
        half4 h;
        h.x = (_Float16)f.x; h.y = (_Float16)f.y; h.z = (_Float16)f.z; h.w = (_Float16)f.w;
        *(half4*)(zh + idx4 * 4) = h;
    }
}

// ---------------------------------------------------------------------------
// MFMA dist kernel v9 (unchanged from round 11 — counters still pending).
// z tile resident in LDS (swizzled slot = c ^ (r&31)); cb per-kt staging
// (v8 swizzle). acc init = -0.5*esq[col]; per-row ARGMAX of acc.
// ---------------------------------------------------------------------------
__global__ __launch_bounds__(256, 2)
void mfma_dist_kernel(const _Float16* __restrict__ zh, const _Float16* __restrict__ ch,
                      const float* __restrict__ esq,
                      float* __restrict__ pd1, int* __restrict__ pi1,
                      float* __restrict__ pd2) {
    __shared__ _Float16 zl[BM * 256];  // 64 KB, resident z tile (swizzled)
    __shared__ _Float16 cs[BV * BK];   // 16 KB, per-kt cb tile (v8 swizzle)
    float* sc_d1 = (float*)zl;         // end-phase alias (3 KB; z dead by then)
    float* sc_d2 = sc_d1 + BM * 2;
    int*   sc_i1 = (int*)(sc_d2 + BM * 2);

    const int row0  = blockIdx.x * BM;
    const int vbase = blockIdx.y * VRANGE;

    const int tid  = threadIdx.x;
    const int w    = tid >> 6;
    const int lane = tid & 63;
    const int lr   = lane & 15;
    const int quad = lane >> 4;
    const int mh   = (w >> 1) * 64;
    const int vh   = (w & 1) * 64;

    // ---- stage z ONCE: wave w covers rows [w*32, w*32+32), 16 DMA instrs ----
    {
        const int rl = lane >> 5;             // 0..1
        const int sc = lane & 31;             // dest slot within row-pair
        #pragma unroll
        for (int i = 0; i < 16; ++i) {
            const int r = w * 32 + i * 2 + rl;
            const int c = sc ^ (i * 2 + rl);  // source chunk (slot ^ (r&31))
            load_lds16(zh + (size_t)(row0 + r) * EMB + c * 8,
                       zl + (size_t)(w * 1024 + i * 64) * 8);
        }
    }

    int rowOffZ[4];
    #pragma unroll
    for (int i = 0; i < 4; ++i) rowOffZ[i] = (mh + i * 16 + lr) * 256;

    const int q7 = quad ^ (lr & 7);
    const int offA0 = q7 * 8;
    const int offA1 = (4 ^ q7) * 8;
    int rB[4];
    #pragma unroll
    for (int j = 0; j < 4; ++j) rB[j] = (vh + j * 16 + lr) * BK;

    const int schunk = (lane & 7) ^ (lane >> 3);

    float m1[16], m2[16]; int i1[16];
    #pragma unroll
    for (int t = 0; t < 16; ++t) { m1[t] = -INFINITY; m2[t] = -INFINITY; i1[t] = 0; }

    float ev[4];
    #pragma unroll
    for (int j = 0; j < 4; ++j) ev[j] = esq[vbase + vh + j * 16 + lr];

    __syncthreads();   // z DMA drained (vmcnt(0) before barrier)

    for (int vt = 0; vt < NVT; ++vt) {
        const int v0 = vbase + vt * BV;
        const _Float16* csrc = ch + (size_t)(v0 + w * 32 + (lane >> 3)) * EMB + schunk * 8;

        floatx4 acc[4][4];
        #pragma unroll
        for (int j = 0; j < 4; ++j) {
            const float e2 = -0.5f * ev[j];
            #pragma unroll
            for (int i = 0; i < 4; ++i) acc[i][j] = (floatx4)e2;
        }
        float evn[4];
        {
            const int vtn = (vt + 1 < NVT) ? vt + 1 : vt;
            #pragma unroll
            for (int j = 0; j < 4; ++j) evn[j] = esq[vbase + vtn * BV + vh + j * 16 + lr];
        }

        #pragma unroll 1
        for (int kt = 0; kt < EMB / BK; ++kt) {
            const int ko = kt * BK;
            #pragma unroll
            for (int q = 0; q < 4; ++q)
                load_lds16(csrc + (size_t)q * 8 * EMB + ko, &cs[w * 2048 + q * 512]);
            __syncthreads();

            #pragma unroll
            for (int s = 0; s < 2; ++s) {
                const int ks = kt * 2 + s;                     // global kstep 0..7
                const int cE = (((ks << 2) | quad) ^ lr) << 3; // z chunk offset, even i
                const int cO = cE ^ 128;                       // odd i
                half8 a[4];
                a[0] = *(const half8*)&zl[rowOffZ[0] + cE];
                a[1] = *(const half8*)&zl[rowOffZ[1] + cO];
                a[2] = *(const half8*)&zl[rowOffZ[2] + cE];
                a[3] = *(const half8*)&zl[rowOffZ[3] + cO];
                const int off = s ? offA1 : offA0;
                #pragma unroll
                for (int j = 0; j < 4; ++j) {
                    const half8 b = *(const half8*)&cs[rB[j] + off];
                    #pragma unroll
                    for (int i = 0; i < 4; ++i)
                        acc[i][j] = __builtin_amdgcn_mfma_f32_16x16x32_f16(a[i], b, acc[i][j], 0, 0, 0);
                }
            }
            __syncthreads();
        }

        int vj[4];
        #pragma unroll
        for (int j = 0; j < 4; ++j) vj[j] = v0 + vh + j * 16 + lr;
        #pragma unroll
        for (int i = 0; i < 4; ++i) {
            #pragma unroll
            for (int reg = 0; reg < 4; ++reg) {
                const int t = i * 4 + reg;
                #pragma unroll
                for (int j = 0; j < 4; ++j) {
                    const float a = acc[i][j][reg];
                    m2[t] = fmaxf(m2[t], fminf(a, m1[t]));
                    i1[t] = (a > m1[t]) ? vj[j] : i1[t];
                    m1[t] = fmaxf(m1[t], a);
                }
            }
        }
        #pragma unroll
        for (int j = 0; j < 4; ++j) ev[j] = evn[j];
    }

    #pragma unroll
    for (int t = 0; t < 16; ++t) {
        float a1 = m1[t], a2 = m2[t]; int ii = i1[t];
        #pragma unroll
        for (int off = 1; off < 16; off <<= 1) {
            const float o1 = __shfl_xor(a1, off, 64);
            const int   oi = __shfl_xor(ii, off, 64);
            const float o2 = __shfl_xor(a2, off, 64);
            if (o1 > a1) { a2 = fmaxf(a1, o2); a1 = o1; ii = oi; }
            else         { a2 = fmaxf(a2, o1); }
        }
        m1[t] = a1; m2[t] = a2; i1[t] = ii;
    }
    if (lr == 0) {
        #pragma unroll
        for (int t = 0; t < 16; ++t) {
            const int r = mh + (t >> 2) * 16 + quad * 4 + (t & 3);
            sc_d1[r * 2 + (w & 1)] = m1[t];
            sc_d2[r * 2 + (w & 1)] = m2[t];
            sc_i1[r * 2 + (w & 1)] = i1[t];
        }
    }
    __syncthreads();
    if (tid < BM) {
        float a1 = sc_d1[tid * 2], a2 = sc_d2[tid * 2]; int ii = sc_i1[tid * 2];
        const float o1 = sc_d1[tid * 2 + 1], o2 = sc_d2[tid * 2 + 1];
        const int   oi = sc_i1[tid * 2 + 1];
        if (o1 > a1) { a2 = fmaxf(a1, o2); a1 = o1; ii = oi; }
        else         { a2 = fmaxf(a2, o1); }
        const size_t o = (size_t)blockIdx.y * N_ROWS + row0 + tid;
        pd1[o] = -2.0f * a1; pi1[o] = ii; pd2[o] = -2.0f * a2;
    }
}

// ---------------------------------------------------------------------------
// Combine: merge VSPLIT top-2 partials; margin >= TAU -> commit, else flag.
// ---------------------------------------------------------------------------
__global__ void combine_kernel(const float* __restrict__ pd1, const int* __restrict__ pi1,
                               const float* __restrict__ pd2,
                               const float* __restrict__ cb,
                               float* __restrict__ tokens, float* __restrict__ zq,
                               float* __restrict__ cnt,
                               int* __restrict__ flagcnt, int* __restrict__ flaglist) {
    const int wave = threadIdx.x >> 6;
    const int lane = threadIdx.x & 63;
    const int row  = blockIdx.x * 4 + wave;

    float d1 = INFINITY, d2 = INFINITY; int i1 = 0;
    #pragma unroll
    for (int s = 0; s < VSPLIT; ++s) {
        const size_t o = (size_t)s * N_ROWS + row;
        const float od1 = pd1[o], od2 = pd2[o]; const int oi1 = pi1[o];
        if (od1 < d1) { d2 = fminf(d1, od2); d1 = od1; i1 = oi1; }
        else          { d2 = fminf(d2, od1); }
    }
    if ((d2 - d1) < TAU) {
        if (lane == 0) {
            const int pos = atomicAdd(flagcnt, 1);
            flaglist[pos] = row;
        }
        return;   // rescue writes this row
    }
    if (lane == 0) {
        tokens[row] = (float)i1;
        atomicAdd(&cnt[i1], 1.0f);
    }
    const float4 v = *(const float4*)(cb + (size_t)i1 * EMB + lane * 4);
    *(float4*)(zq + (size_t)row * EMB + lane * 4) = v;
}

// ---------------------------------------------------------------------------
// Rescue v5 + explicit VGPR budget. Round 11: without __launch_bounds__ the
// allocator clamps to 64 VGPRs and spills zv[4][4] (791 MB scratch writes,
// 631 us). (256,2) budgets ~256 VGPRs/wave; actual need ~120 -> no spill.
// Job = (row-quad, 64-code chunk) per wave; each cb read serves 4 rows.
// ---------------------------------------------------------------------------
__global__ __launch_bounds__(256, 2)
void rescue5_kernel(const int* __restrict__ flagcnt, const int* __restrict__ flaglist,
                    const float* __restrict__ z, const float* __restrict__ cb,
                    const float* __restrict__ esq,
                    unsigned long long* __restrict__ rkey) {
    const int tid  = threadIdx.x;
    const int w    = tid >> 6;
    const int lane = tid & 63;
    const int g    = lane >> 2;        // code group 0..15
    const int s    = lane & 3;         // sub-lane: dims k*16 + s*4
    const int n = *flagcnt;
    if (n == 0) return;
    const int nq = (n + 3) >> 2;       // row quads
    const int waveId = blockIdx.x * 4 + w;
    const int nwaves = gridDim.x * 4;
    const int njobs  = nq * 128;       // 128 chunks of 64 codes per row-quad
    for (int j = waveId; j < njobs; j += nwaves) {
        const int qt = j >> 7;
        const int c0 = (j & 127) * 64;
        int rows[4];
        #pragma unroll
        for (int r = 0; r < 4; ++r) {
            int f = qt * 4 + r; if (f >= n) f = n - 1;
            rows[r] = flaglist[f];
        }
        float p[4][4];                 // [gs][row]
        #pragma unroll
        for (int gs = 0; gs < 4; ++gs)
            #pragma unroll
            for (int r = 0; r < 4; ++r) p[gs][r] = 0.0f;
        #pragma unroll
        for (int kb = 0; kb < 4; ++kb) {
            float4 zv[4][4];           // [row][kk]
            #pragma unroll
            for (int r = 0; r < 4; ++r)
                #pragma unroll
                for (int kk = 0; kk < 4; ++kk)
                    zv[r][kk] = *(const float4*)(z + (size_t)rows[r] * EMB + (kb * 4 + kk) * 16 + s * 4);
            #pragma unroll
            for (int gs = 0; gs < 4; ++gs) {
                const float* cr = cb + (size_t)(c0 + gs * 16 + g) * EMB;
                #pragma unroll
                for (int kk = 0; kk < 4; ++kk) {
                    const float4 c4 = *(const float4*)(cr + (kb * 4 + kk) * 16 + s * 4);
                    #pragma unroll
                    for (int r = 0; r < 4; ++r)
                        p[gs][r] += zv[r][kk].x * c4.x + zv[r][kk].y * c4.y
                                  + zv[r][kk].z * c4.z + zv[r][kk].w * c4.w;
                }
            }
        }
        #pragma unroll
        for (int r = 0; r < 4; ++r) {
            float bd = INFINITY; int bv = 0;
            #pragma unroll
            for (int gs = 0; gs < 4; ++gs) {
                float pp = p[gs][r];
                pp += __shfl_xor(pp, 1, 64);
                pp += __shfl_xor(pp, 2, 64);   // 4 quad-lanes hold full dot
                const int v = c0 + gs * 16 + g;
                const float d = esq[v] - 2.0f * pp;
                if (d < bd) { bd = d; bv = v; } // gs ascending -> lowest tie idx
            }
            #pragma unroll
            for (int off = 4; off < 64; off <<= 1) {
                const float od = __shfl_xor(bd, off, 64);
                const int   ov = __shfl_xor(bv, off, 64);
                if (od < bd || (od == bd && ov < bv)) { bd = od; bv = ov; }
            }
            if (lane == 0) {
                unsigned int u = __float_as_uint(bd);
                u = (u & 0x80000000u) ? ~u : (u | 0x80000000u);
                atomicMin(rkey + rows[r], ((unsigned long long)u << 32) | (unsigned int)bv);
            }
        }
    }
}

// ---------------------------------------------------------------------------
// Rescue writer: separate dispatch (kernel boundary = visibility ordering).
// ---------------------------------------------------------------------------
__global__ void rescue_write_kernel(const int* __restrict__ flagcnt,
                                    const int* __restrict__ flaglist,
                                    const unsigned long long* __restrict__ rkey,
                                    const float* __restrict__ cb,
                                    float* __restrict__ tokens, float* __restrict__ zq,
                                    float* __restrict__ cnt) {
    const int w    = threadIdx.x >> 6;
    const int lane = threadIdx.x & 63;
    const int n = *flagcnt;
    for (int f = blockIdx.x * 4 + w; f < n; f += gridDim.x * 4) {
        const int row = flaglist[f];
        const int v = (int)(unsigned int)(rkey[row] & 0xFFFFFFFFull);
        if (lane == 0) {
            tokens[row] = (float)v;
            atomicAdd(&cnt[v], 1.0f);
        }
        const float4 c4 = *(const float4*)(cb + (size_t)v * EMB + lane * 4);
        *(float4*)(zq + (size_t)row * EMB + lane * 4) = c4;
    }
}

// ===========================================================================
// Fallback (round-3 fp32 path) if ws is too small.
// ===========================================================================
__global__ void esq_kernel(const float* __restrict__ cb, float* __restrict__ esq) {
    const int wave = threadIdx.x >> 6;
    const int lane = threadIdx.x & 63;
    const int row  = blockIdx.x * 4 + wave;
    const float4 v = *(const float4*)(cb + (size_t)row * EMB + lane * 4);
    float s = v.x * v.x + v.y * v.y + v.z * v.z + v.w * v.w;
    #pragma unroll
    for (int off = 32; off > 0; off >>= 1) s += __shfl_down(s, off, 64);
    if (lane == 0) esq[row] = s;
}

#define FLSTR 36
__global__ __launch_bounds__(256, 2)
void fb_dist_kernel(const float* __restrict__ z, const float* __restrict__ cb,
                    const float* __restrict__ esq,
                    float* __restrict__ pdist, int* __restrict__ pidx) {
    __shared__ float zs[BM][FLSTR];
    __shared__ float es[BV][FLSTR];
    __shared__ float rdist[16][16];
    __shared__ int   ridx [16][16];
    const int row0 = blockIdx.x * BM, vbase = blockIdx.y * VRANGE;
    const int tid = threadIdx.x, wave = tid >> 6, lane = tid & 63;
    const int wly = (lane >> 3) & 7, wlx = lane & 7;
    const int wbase = (wave >> 1) * 64, cbase = (wave & 1) * 64;
    const int arow = wbase + wly, bcol = cbase + wlx;
    const int rowSlot = (wave >> 1) * 8 + wly, colSlot = (wave & 1) * 8 + wlx;
    const int sc4 = tid & 7, sr0 = tid >> 3;
    float best[8]; int bidx[8];
    #pragma unroll
    for (int i = 0; i < 8; ++i) { best[i] = INFINITY; bidx[i] = 0; }
    for (int vt = 0; vt < NVT; ++vt) {
        const int v0 = vbase + vt * BV;
        float acc[8][8];
        #pragma unroll
        for (int i = 0; i < 8; ++i)
            #pragma unroll
            for (int j = 0; j < 8; ++j) acc[i][j] = 0.0f;
        #pragma unroll 1
        for (int kt = 0; kt < EMB / 32; ++kt) {
            #pragma unroll
            for (int t = 0; t < 4; ++t) {
                const int r = sr0 + 32 * t;
                *(float4*)&zs[r][sc4 * 4] = *(const float4*)(z  + (size_t)(row0 + r) * EMB + kt * 32 + sc4 * 4);
                *(float4*)&es[r][sc4 * 4] = *(const float4*)(cb + (size_t)(v0 + r) * EMB + kt * 32 + sc4 * 4);
            }
            __syncthreads();
            #pragma unroll 1
            for (int k0 = 0; k0 < 8; ++k0) {
                const int kk = k0 * 4;
                float a[8][4];
                #pragma unroll
                for (int i = 0; i < 8; ++i) {
                    const float4 a4 = *(const float4*)&zs[arow + 8 * i][kk];
                    a[i][0] = a4.x; a[i][1] = a4.y; a[i][2] = a4.z; a[i][3] = a4.w;
                }
                #pragma unroll
                for (int j = 0; j < 8; ++j) {
                    const float4 b4 = *(const float4*)&es[bcol + 8 * j][kk];
                    #pragma unroll
                    for (int i = 0; i < 8; ++i) {
                        acc[i][j] += a[i][0] * b4.x; acc[i][j] += a[i][1] * b4.y;
                        acc[i][j] += a[i][2] * b4.z; acc[i][j] += a[i][3] * b4.w;
                    }
                }
            }
            __syncthreads();
        }
        #pragma unroll
        for (int j = 0; j < 8; ++j) {
            const int v = v0 + bcol + 8 * j;
            const float evv = esq[v];
            #pragma unroll
            for (int i = 0; i < 8; ++i) {
                const float d = evv - 2.0f * acc[i][j];
                if (d < best[i]) { best[i] = d; bidx[i] = v; }
            }
        }
    }
    for (int i = 0; i < 8; ++i) {
        rdist[rowSlot][colSlot] = best[i];
        ridx [rowSlot][colSlot] = bidx[i];
        __syncthreads();
        if (colSlot == 0) {
            float bd = rdist[rowSlot][0]; int bi = ridx[rowSlot][0];
            #pragma unroll
            for (int t = 1; t < 16; ++t) {
                const float d = rdist[rowSlot][t]; const int ii = ridx[rowSlot][t];
                if (d < bd || (d == bd && ii < bi)) { bd = d; bi = ii; }
            }
            const int row = row0 + wbase + 8 * i + wly;
            pdist[(size_t)blockIdx.y * N_ROWS + row] = bd;
            pidx [(size_t)blockIdx.y * N_ROWS + row] = bi;
        }
        __syncthreads();
    }
}

__global__ void fb_combine_kernel(const float* __restrict__ pdist, const int* __restrict__ pidx,
                                  const float* __restrict__ cb,
                                  float* __restrict__ tokens, float* __restrict__ zq,
                                  float* __restrict__ cnt) {
    const int wave = threadIdx.x >> 6, lane = threadIdx.x & 63;
    const int row = blockIdx.x * 4 + wave;
    float bd = INFINITY; int bi = 0;
    #pragma unroll
    for (int s = 0; s < VSPLIT; ++s) {
        const float d = pdist[(size_t)s * N_ROWS + row];
        const int ii  = pidx [(size_t)s * N_ROWS + row];
        if (d < bd || (d == bd && ii < bi)) { bd = d; bi = ii; }
    }
    if (lane == 0) { tokens[row] = (float)bi; atomicAdd(&cnt[bi], 1.0f); }
    const float4 v = *(const float4*)(cb + (size_t)bi * EMB + lane * 4);
    *(float4*)(zq + (size_t)row * EMB + lane * 4) = v;
}

// ---------------------------------------------------------------------------
// d_out: [0,N) tokens | [N, N+N*EMB) zq | +VOCAB ref_count
// ws: zh | ch | esq | pd1|pd2|pi1 | rkey | flagcnt | flaglist  ~= 13.8 MB
// 5 dispatches: prep -> mfma_dist -> combine -> rescue5 -> rescue_write
// ---------------------------------------------------------------------------
extern "C" void kernel_launch(void* const* d_in, const int* in_sizes, int n_in,
                              void* d_out, int out_size, void* d_ws, size_t ws_size,
                              hipStream_t stream) {
    const float* z  = (const float*)d_in[0];
    const float* cb = (const float*)d_in[1];

    float* out    = (float*)d_out;
    float* tokens = out;
    float* zq     = out + N_ROWS;
    float* cnt    = out + N_ROWS + (size_t)N_ROWS * EMB;

    const size_t ZE = (size_t)N_ROWS * EMB, CE = (size_t)VOCAB * EMB, P = (size_t)VSPLIT * N_ROWS;
    const size_t NEED = (ZE + CE) * sizeof(_Float16) + VOCAB * 4
                      + 3 * P * 4 + (size_t)N_ROWS * 8 + 256 + N_ROWS * 4;

    if (ws_size >= NEED) {
        char* p = (char*)d_ws;
        _Float16* zh = (_Float16*)p;            p += ZE * 2;
        _Float16* ch = (_Float16*)p;            p += CE * 2;
        float* esq   = (float*)p;               p += VOCAB * 4;
        float* pd1   = (float*)p;               p += P * 4;
        float* pd2   = (float*)p;               p += P * 4;
        int*   pi1   = (int*)p;                 p += P * 4;
        unsigned long long* rkey = (unsigned long long*)p;  p += (size_t)N_ROWS * 8;
        int*   flagcnt = (int*)p;               p += 256;
        int*   flaglist = (int*)p;

        prep_kernel<<<VOCAB / 4 + (int)(ZE / 4 / 256), 256, 0, stream>>>(
            z, cb, zh, ch, esq, cnt, rkey, flagcnt);
        mfma_dist_kernel<<<dim3(N_ROWS / BM, VSPLIT), 256, 0, stream>>>(
            zh, ch, esq, pd1, pi1, pd2);
        combine_kernel<<<N_ROWS / 4, 256, 0, stream>>>(
            pd1, pi1, pd2, cb, tokens, zq, cnt, flagcnt, flaglist);
        rescue5_kernel<<<2048, 256, 0, stream>>>(flagcnt, flaglist, z, cb, esq, rkey);
        rescue_write_kernel<<<32, 256, 0, stream>>>(flagcnt, flaglist, rkey, cb, tokens, zq, cnt);
    } else {
        float* esq   = (float*)d_ws;
        float* pdist = esq + VOCAB;
        int*   pidx  = (int*)(pdist + P);
        hipMemsetAsync(cnt, 0, VOCAB * sizeof(float), stream);
        esq_kernel<<<VOCAB / 4, 256, 0, stream>>>(cb, esq);
        fb_dist_kernel<<<dim3(N_ROWS / BM, VSPLIT), 256, 0, stream>>>(z, cb, esq, pdist, pidx);
        fb_combine_kernel<<<N_ROWS / 4, 256, 0, stream>>>(pdist, pidx, cb, tokens, zq, cnt);
    }
}

// Round 13
// 471.329 us; speedup vs baseline: 1.7155x; 1.1017x over previous
//
#include <hip/hip_runtime.h>
#include <math.h>

#define N_ROWS 16384
#define VOCAB  8192
#define EMB    256

// ---- MFMA path tiling ----
#define BM 128
#define BV 128
#define BK 64                      // halfs per staged cb K-chunk (2 MFMA k-steps)
#define VSPLIT 8                   // grid (128, 8)
#define VRANGE (VOCAB / VSPLIT)    // 1024
#define NVT    (VRANGE / BV)       // 8
#define TAU 0.15f                  // >= 2*max|dist err| over 1.3e8 pairs (fp16 inputs)

typedef _Float16 half8 __attribute__((ext_vector_type(8)));
typedef _Float16 half4 __attribute__((ext_vector_type(4)));
typedef float floatx4 __attribute__((ext_vector_type(4)));

// async global->LDS DMA, 16 B/lane; LDS dest = wave-uniform base + lane*16
__device__ __forceinline__ void load_lds16(const _Float16* g, _Float16* l) {
    __builtin_amdgcn_global_load_lds(
        (const __attribute__((address_space(1))) void*)g,
        (__attribute__((address_space(3))) void*)l, 16, 0, 0);
}

// ---------------------------------------------------------------------------
// PREP (1 dispatch: esq + fp16 convert + output/scratch init).
// ---------------------------------------------------------------------------
__global__ void prep_kernel(const float* __restrict__ z, const float* __restrict__ cb,
                            _Float16* __restrict__ zh, _Float16* __restrict__ ch,
                            float* __restrict__ esq, float* __restrict__ cnt,
                            unsigned long long* __restrict__ rkey,
                            int* __restrict__ flagcnt) {
    const int b = blockIdx.x, t = threadIdx.x;
    if (b < VOCAB / 4) {
        const int row  = b * 4 + (t >> 6);
        const int lane = t & 63;
        const float4 f = *(const float4*)(cb + (size_t)row * EMB + lane * 4);
        half4 h;
        h.x = (_Float16)f.x; h.y = (_Float16)f.y; h.z = (_Float16)f.z; h.w = (_Float16)f.w;
        *(half4*)(ch + (size_t)row * EMB + lane * 4) = h;
        float s = f.x * f.x + f.y * f.y + f.z * f.z + f.w * f.w;
        #pragma unroll
        for (int off = 32; off > 0; off >>= 1) s += __shfl_down(s, off, 64);
        if (lane == 0) esq[row] = s;
        if (t < 4) cnt[b * 4 + t] = 0.0f;
        if (t >= 8 && t < 16) rkey[b * 8 + (t - 8)] = ~0ull;
        if (b == 0 && t == 4) *flagcnt = 0;
    } else {
        const size_t idx4 = (size_t)(b - VOCAB / 4) * 256 + t;
        const float4 f = *(const float4*)(z + idx4 * 4);
        half4 h;
        h.x = (_Float16)f.x; h.y = (_Float16)f.y; h.z = (_Float16)f.z; h.w = (_Float16)f.w;
        *(half4*)(zh + idx4 * 4) = h;
    }
}

// ---------------------------------------------------------------------------
// MFMA dist kernel v9 (unchanged — counters still pending this round).
// z tile resident in LDS (swizzled slot = c ^ (r&31)); cb per-kt staging
// (v8 swizzle). acc init = -0.5*esq[col]; per-row ARGMAX of acc.
// ---------------------------------------------------------------------------
__global__ __launch_bounds__(256, 2)
void mfma_dist_kernel(const _Float16* __restrict__ zh, const _Float16* __restrict__ ch,
                      const float* __restrict__ esq,
                      float* __restrict__ pd1, int* __restrict__ pi1,
                      float* __restrict__ pd2) {
    __shared__ _Float16 zl[BM * 256];  // 64 KB, resident z tile (swizzled)
    __shared__ _Float16 cs[BV * BK];   // 16 KB, per-kt cb tile (v8 swizzle)
    float* sc_d1 = (float*)zl;         // end-phase alias (3 KB; z dead by then)
    float* sc_d2 = sc_d1 + BM * 2;
    int*   sc_i1 = (int*)(sc_d2 + BM * 2);

    const int row0  = blockIdx.x * BM;
    const int vbase = blockIdx.y * VRANGE;

    const int tid  = threadIdx.x;
    const int w    = tid >> 6;
    const int lane = tid & 63;
    const int lr   = lane & 15;
    const int quad = lane >> 4;
    const int mh   = (w >> 1) * 64;
    const int vh   = (w & 1) * 64;

    // ---- stage z ONCE ----
    {
        const int rl = lane >> 5;
        const int sc = lane & 31;
        #pragma unroll
        for (int i = 0; i < 16; ++i) {
            const int r = w * 32 + i * 2 + rl;
            const int c = sc ^ (i * 2 + rl);
            load_lds16(zh + (size_t)(row0 + r) * EMB + c * 8,
                       zl + (size_t)(w * 1024 + i * 64) * 8);
        }
    }

    int rowOffZ[4];
    #pragma unroll
    for (int i = 0; i < 4; ++i) rowOffZ[i] = (mh + i * 16 + lr) * 256;

    const int q7 = quad ^ (lr & 7);
    const int offA0 = q7 * 8;
    const int offA1 = (4 ^ q7) * 8;
    int rB[4];
    #pragma unroll
    for (int j = 0; j < 4; ++j) rB[j] = (vh + j * 16 + lr) * BK;

    const int schunk = (lane & 7) ^ (lane >> 3);

    float m1[16], m2[16]; int i1[16];
    #pragma unroll
    for (int t = 0; t < 16; ++t) { m1[t] = -INFINITY; m2[t] = -INFINITY; i1[t] = 0; }

    float ev[4];
    #pragma unroll
    for (int j = 0; j < 4; ++j) ev[j] = esq[vbase + vh + j * 16 + lr];

    __syncthreads();   // z DMA drained

    for (int vt = 0; vt < NVT; ++vt) {
        const int v0 = vbase + vt * BV;
        const _Float16* csrc = ch + (size_t)(v0 + w * 32 + (lane >> 3)) * EMB + schunk * 8;

        floatx4 acc[4][4];
        #pragma unroll
        for (int j = 0; j < 4; ++j) {
            const float e2 = -0.5f * ev[j];
            #pragma unroll
            for (int i = 0; i < 4; ++i) acc[i][j] = (floatx4)e2;
        }
        float evn[4];
        {
            const int vtn = (vt + 1 < NVT) ? vt + 1 : vt;
            #pragma unroll
            for (int j = 0; j < 4; ++j) evn[j] = esq[vbase + vtn * BV + vh + j * 16 + lr];
        }

        #pragma unroll 1
        for (int kt = 0; kt < EMB / BK; ++kt) {
            const int ko = kt * BK;
            #pragma unroll
            for (int q = 0; q < 4; ++q)
                load_lds16(csrc + (size_t)q * 8 * EMB + ko, &cs[w * 2048 + q * 512]);
            __syncthreads();

            #pragma unroll
            for (int s = 0; s < 2; ++s) {
                const int ks = kt * 2 + s;
                const int cE = (((ks << 2) | quad) ^ lr) << 3;
                const int cO = cE ^ 128;
                half8 a[4];
                a[0] = *(const half8*)&zl[rowOffZ[0] + cE];
                a[1] = *(const half8*)&zl[rowOffZ[1] + cO];
                a[2] = *(const half8*)&zl[rowOffZ[2] + cE];
                a[3] = *(const half8*)&zl[rowOffZ[3] + cO];
                const int off = s ? offA1 : offA0;
                #pragma unroll
                for (int j = 0; j < 4; ++j) {
                    const half8 b = *(const half8*)&cs[rB[j] + off];
                    #pragma unroll
                    for (int i = 0; i < 4; ++i)
                        acc[i][j] = __builtin_amdgcn_mfma_f32_16x16x32_f16(a[i], b, acc[i][j], 0, 0, 0);
                }
            }
            __syncthreads();
        }

        int vj[4];
        #pragma unroll
        for (int j = 0; j < 4; ++j) vj[j] = v0 + vh + j * 16 + lr;
        #pragma unroll
        for (int i = 0; i < 4; ++i) {
            #pragma unroll
            for (int reg = 0; reg < 4; ++reg) {
                const int t = i * 4 + reg;
                #pragma unroll
                for (int j = 0; j < 4; ++j) {
                    const float a = acc[i][j][reg];
                    m2[t] = fmaxf(m2[t], fminf(a, m1[t]));
                    i1[t] = (a > m1[t]) ? vj[j] : i1[t];
                    m1[t] = fmaxf(m1[t], a);
                }
            }
        }
        #pragma unroll
        for (int j = 0; j < 4; ++j) ev[j] = evn[j];
    }

    #pragma unroll
    for (int t = 0; t < 16; ++t) {
        float a1 = m1[t], a2 = m2[t]; int ii = i1[t];
        #pragma unroll
        for (int off = 1; off < 16; off <<= 1) {
            const float o1 = __shfl_xor(a1, off, 64);
            const int   oi = __shfl_xor(ii, off, 64);
            const float o2 = __shfl_xor(a2, off, 64);
            if (o1 > a1) { a2 = fmaxf(a1, o2); a1 = o1; ii = oi; }
            else         { a2 = fmaxf(a2, o1); }
        }
        m1[t] = a1; m2[t] = a2; i1[t] = ii;
    }
    if (lr == 0) {
        #pragma unroll
        for (int t = 0; t < 16; ++t) {
            const int r = mh + (t >> 2) * 16 + quad * 4 + (t & 3);
            sc_d1[r * 2 + (w & 1)] = m1[t];
            sc_d2[r * 2 + (w & 1)] = m2[t];
            sc_i1[r * 2 + (w & 1)] = i1[t];
        }
    }
    __syncthreads();
    if (tid < BM) {
        float a1 = sc_d1[tid * 2], a2 = sc_d2[tid * 2]; int ii = sc_i1[tid * 2];
        const float o1 = sc_d1[tid * 2 + 1], o2 = sc_d2[tid * 2 + 1];
        const int   oi = sc_i1[tid * 2 + 1];
        if (o1 > a1) { a2 = fmaxf(a1, o2); a1 = o1; ii = oi; }
        else         { a2 = fmaxf(a2, o1); }
        const size_t o = (size_t)blockIdx.y * N_ROWS + row0 + tid;
        pd1[o] = -2.0f * a1; pi1[o] = ii; pd2[o] = -2.0f * a2;
    }
}

// ---------------------------------------------------------------------------
// Combine: merge VSPLIT top-2 partials; margin >= TAU -> commit, else flag.
// ---------------------------------------------------------------------------
__global__ void combine_kernel(const float* __restrict__ pd1, const int* __restrict__ pi1,
                               const float* __restrict__ pd2,
                               const float* __restrict__ cb,
                               float* __restrict__ tokens, float* __restrict__ zq,
                               float* __restrict__ cnt,
                               int* __restrict__ flagcnt, int* __restrict__ flaglist) {
    const int wave = threadIdx.x >> 6;
    const int lane = threadIdx.x & 63;
    const int row  = blockIdx.x * 4 + wave;

    float d1 = INFINITY, d2 = INFINITY; int i1 = 0;
    #pragma unroll
    for (int s = 0; s < VSPLIT; ++s) {
        const size_t o = (size_t)s * N_ROWS + row;
        const float od1 = pd1[o], od2 = pd2[o]; const int oi1 = pi1[o];
        if (od1 < d1) { d2 = fminf(d1, od2); d1 = od1; i1 = oi1; }
        else          { d2 = fminf(d2, od1); }
    }
    if ((d2 - d1) < TAU) {
        if (lane == 0) {
            const int pos = atomicAdd(flagcnt, 1);
            flaglist[pos] = row;
        }
        return;   // rescue writes this row
    }
    if (lane == 0) {
        tokens[row] = (float)i1;
        atomicAdd(&cnt[i1], 1.0f);
    }
    const float4 v = *(const float4*)(cb + (size_t)i1 * EMB + lane * 4);
    *(float4*)(zq + (size_t)row * EMB + lane * 4) = v;
}

// ---------------------------------------------------------------------------
// Rescue v6: CODEBOOK-STATIONARY. Rounds 11/12 proved the row-stationary
// rescue needs >128 live VGPRs and always spills. Invert the loops:
// block b stages codes [b*32, b*32+32) in LDS (32 KB fp32, read from HBM
// exactly once) and iterates over ALL flagged rows, 2 at a time for ILP.
// Wave: 8 codes x 8 lanes/code (lane covers dims in stride-8 float4 steps);
// 3-deep shuffle dot-reduce + 3-deep min-merge; 1 atomicMin per wave/row.
// Register footprint ~40 VGPRs -> no spill by construction.
// ---------------------------------------------------------------------------
__global__ void rescue6_kernel(const int* __restrict__ flagcnt, const int* __restrict__ flaglist,
                               const float* __restrict__ z, const float* __restrict__ cb,
                               const float* __restrict__ esq,
                               unsigned long long* __restrict__ rkey) {
    __shared__ float cbs[32 * 256];   // 32 KB
    __shared__ float esqs[32];
    const int b   = blockIdx.x;       // codes [b*32, b*32+32)
    const int tid = threadIdx.x;
    const int w   = tid >> 6;
    const int lane = tid & 63;
    const int v0  = b * 32;

    for (int i = tid; i < 32 * 64; i += 256)
        *(float4*)&cbs[i * 4] = *(const float4*)(cb + (size_t)v0 * EMB + i * 4);
    if (tid < 32) esqs[tid] = esq[v0 + tid];
    __syncthreads();

    const int n = *flagcnt;
    const int code = w * 8 + (lane >> 3);   // 0..31
    const int l0   = lane & 7;              // dim slice
    const float* crow = &cbs[code * EMB];
    const float ev = esqs[code];
    const int v = v0 + code;

    for (int f = 0; f < n; f += 2) {
        const int rA = flaglist[f];
        const int rB = flaglist[(f + 1 < n) ? f + 1 : f];
        const float* zA = z + (size_t)rA * EMB;
        const float* zB = z + (size_t)rB * EMB;
        float pA = 0.0f, pB = 0.0f;
        #pragma unroll
        for (int kk = 0; kk < 8; ++kk) {
            const int idx = (l0 + 8 * kk) * 4;
            const float4 cv = *(const float4*)&crow[idx];
            const float4 a4 = *(const float4*)(zA + idx);
            const float4 b4 = *(const float4*)(zB + idx);
            pA += a4.x * cv.x + a4.y * cv.y + a4.z * cv.z + a4.w * cv.w;
            pB += b4.x * cv.x + b4.y * cv.y + b4.z * cv.z + b4.w * cv.w;
        }
        #pragma unroll
        for (int off = 1; off < 8; off <<= 1) {
            pA += __shfl_xor(pA, off, 64);
            pB += __shfl_xor(pB, off, 64);
        }
        float dA = ev - 2.0f * pA; int vA = v;
        float dB = ev - 2.0f * pB; int vB = v;
        #pragma unroll
        for (int off = 8; off < 64; off <<= 1) {
            const float oA = __shfl_xor(dA, off, 64); const int ovA = __shfl_xor(vA, off, 64);
            if (oA < dA || (oA == dA && ovA < vA)) { dA = oA; vA = ovA; }
            const float oB = __shfl_xor(dB, off, 64); const int ovB = __shfl_xor(vB, off, 64);
            if (oB < dB || (oB == dB && ovB < vB)) { dB = oB; vB = ovB; }
        }
        if (lane == 0) {
            unsigned int uA = __float_as_uint(dA);
            uA = (uA & 0x80000000u) ? ~uA : (uA | 0x80000000u);
            atomicMin(rkey + rA, ((unsigned long long)uA << 32) | (unsigned int)vA);
            unsigned int uB = __float_as_uint(dB);
            uB = (uB & 0x80000000u) ? ~uB : (uB | 0x80000000u);
            atomicMin(rkey + rB, ((unsigned long long)uB << 32) | (unsigned int)vB);
        }
    }
}

// ---------------------------------------------------------------------------
// Rescue writer: separate dispatch (kernel boundary = visibility ordering).
// ---------------------------------------------------------------------------
__global__ void rescue_write_kernel(const int* __restrict__ flagcnt,
                                    const int* __restrict__ flaglist,
                                    const unsigned long long* __restrict__ rkey,
                                    const float* __restrict__ cb,
                                    float* __restrict__ tokens, float* __restrict__ zq,
                                    float* __restrict__ cnt) {
    const int w    = threadIdx.x >> 6;
    const int lane = threadIdx.x & 63;
    const int n = *flagcnt;
    for (int f = blockIdx.x * 4 + w; f < n; f += gridDim.x * 4) {
        const int row = flaglist[f];
        const int v = (int)(unsigned int)(rkey[row] & 0xFFFFFFFFull);
        if (lane == 0) {
            tokens[row] = (float)v;
            atomicAdd(&cnt[v], 1.0f);
        }
        const float4 c4 = *(const float4*)(cb + (size_t)v * EMB + lane * 4);
        *(float4*)(zq + (size_t)row * EMB + lane * 4) = c4;
    }
}

// ===========================================================================
// Fallback (round-3 fp32 path) if ws is too small.
// ===========================================================================
__global__ void esq_kernel(const float* __restrict__ cb, float* __restrict__ esq) {
    const int wave = threadIdx.x >> 6;
    const int lane = threadIdx.x & 63;
    const int row  = blockIdx.x * 4 + wave;
    const float4 v = *(const float4*)(cb + (size_t)row * EMB + lane * 4);
    float s = v.x * v.x + v.y * v.y + v.z * v.z + v.w * v.w;
    #pragma unroll
    for (int off = 32; off > 0; off >>= 1) s += __shfl_down(s, off, 64);
    if (lane == 0) esq[row] = s;
}

#define FLSTR 36
__global__ __launch_bounds__(256, 2)
void fb_dist_kernel(const float* __restrict__ z, const float* __restrict__ cb,
                    const float* __restrict__ esq,
                    float* __restrict__ pdist, int* __restrict__ pidx) {
    __shared__ float zs[BM][FLSTR];
    __shared__ float es[BV][FLSTR];
    __shared__ float rdist[16][16];
    __shared__ int   ridx [16][16];
    const int row0 = blockIdx.x * BM, vbase = blockIdx.y * VRANGE;
    const int tid = threadIdx.x, wave = tid >> 6, lane = tid & 63;
    const int wly = (lane >> 3) & 7, wlx = lane & 7;
    const int wbase = (wave >> 1) * 64, cbase = (wave & 1) * 64;
    const int arow = wbase + wly, bcol = cbase + wlx;
    const int rowSlot = (wave >> 1) * 8 + wly, colSlot = (wave & 1) * 8 + wlx;
    const int sc4 = tid & 7, sr0 = tid >> 3;
    float best[8]; int bidx[8];
    #pragma unroll
    for (int i = 0; i < 8; ++i) { best[i] = INFINITY; bidx[i] = 0; }
    for (int vt = 0; vt < NVT; ++vt) {
        const int v0 = vbase + vt * BV;
        float acc[8][8];
        #pragma unroll
        for (int i = 0; i < 8; ++i)
            #pragma unroll
            for (int j = 0; j < 8; ++j) acc[i][j] = 0.0f;
        #pragma unroll 1
        for (int kt = 0; kt < EMB / 32; ++kt) {
            #pragma unroll
            for (int t = 0; t < 4; ++t) {
                const int r = sr0 + 32 * t;
                *(float4*)&zs[r][sc4 * 4] = *(const float4*)(z  + (size_t)(row0 + r) * EMB + kt * 32 + sc4 * 4);
                *(float4*)&es[r][sc4 * 4] = *(const float4*)(cb + (size_t)(v0 + r) * EMB + kt * 32 + sc4 * 4);
            }
            __syncthreads();
            #pragma unroll 1
            for (int k0 = 0; k0 < 8; ++k0) {
                const int kk = k0 * 4;
                float a[8][4];
                #pragma unroll
                for (int i = 0; i < 8; ++i) {
                    const float4 a4 = *(const float4*)&zs[arow + 8 * i][kk];
                    a[i][0] = a4.x; a[i][1] = a4.y; a[i][2] = a4.z; a[i][3] = a4.w;
                }
                #pragma unroll
                for (int j = 0; j < 8; ++j) {
                    const float4 b4 = *(const float4*)&es[bcol + 8 * j][kk];
                    #pragma unroll
                    for (int i = 0; i < 8; ++i) {
                        acc[i][j] += a[i][0] * b4.x; acc[i][j] += a[i][1] * b4.y;
                        acc[i][j] += a[i][2] * b4.z; acc[i][j] += a[i][3] * b4.w;
                    }
                }
            }
            __syncthreads();
        }
        #pragma unroll
        for (int j = 0; j < 8; ++j) {
            const int v = v0 + bcol + 8 * j;
            const float evv = esq[v];
            #pragma unroll
            for (int i = 0; i < 8; ++i) {
                const float d = evv - 2.0f * acc[i][j];
                if (d < best[i]) { best[i] = d; bidx[i] = v; }
            }
        }
    }
    for (int i = 0; i < 8; ++i) {
        rdist[rowSlot][colSlot] = best[i];
        ridx [rowSlot][colSlot] = bidx[i];
        __syncthreads();
        if (colSlot == 0) {
            float bd = rdist[rowSlot][0]; int bi = ridx[rowSlot][0];
            #pragma unroll
            for (int t = 1; t < 16; ++t) {
                const float d = rdist[rowSlot][t]; const int ii = ridx[rowSlot][t];
                if (d < bd || (d == bd && ii < bi)) { bd = d; bi = ii; }
            }
            const int row = row0 + wbase + 8 * i + wly;
            pdist[(size_t)blockIdx.y * N_ROWS + row] = bd;
            pidx [(size_t)blockIdx.y * N_ROWS + row] = bi;
        }
        __syncthreads();
    }
}

__global__ void fb_combine_kernel(const float* __restrict__ pdist, const int* __restrict__ pidx,
                                  const float* __restrict__ cb,
                                  float* __restrict__ tokens, float* __restrict__ zq,
                                  float* __restrict__ cnt) {
    const int wave = threadIdx.x >> 6, lane = threadIdx.x & 63;
    const int row = blockIdx.x * 4 + wave;
    float bd = INFINITY; int bi = 0;
    #pragma unroll
    for (int s = 0; s < VSPLIT; ++s) {
        const float d = pdist[(size_t)s * N_ROWS + row];
        const int ii  = pidx [(size_t)s * N_ROWS + row];
        if (d < bd || (d == bd && ii < bi)) { bd = d; bi = ii; }
    }
    if (lane == 0) { tokens[row] = (float)bi; atomicAdd(&cnt[bi], 1.0f); }
    const float4 v = *(const float4*)(cb + (size_t)bi * EMB + lane * 4);
    *(float4*)(zq + (size_t)row * EMB + lane * 4) = v;
}

// ---------------------------------------------------------------------------
// d_out: [0,N) tokens | [N, N+N*EMB) zq | +VOCAB ref_count
// ws: zh | ch | esq | pd1|pd2|pi1 | rkey | flagcnt | flaglist  ~= 13.8 MB
// 5 dispatches: prep -> mfma_dist -> combine -> rescue6 -> rescue_write
// ---------------------------------------------------------------------------
extern "C" void kernel_launch(void* const* d_in, const int* in_sizes, int n_in,
                              void* d_out, int out_size, void* d_ws, size_t ws_size,
                              hipStream_t stream) {
    const float* z  = (const float*)d_in[0];
    const float* cb = (const float*)d_in[1];

    float* out    = (float*)d_out;
    float* tokens = out;
    float* zq     = out + N_ROWS;
    float* cnt    = out + N_ROWS + (size_t)N_ROWS * EMB;

    const size_t ZE = (size_t)N_ROWS * EMB, CE = (size_t)VOCAB * EMB, P = (size_t)VSPLIT * N_ROWS;
    const size_t NEED = (ZE + CE) * sizeof(_Float16) + VOCAB * 4
                      + 3 * P * 4 + (size_t)N_ROWS * 8 + 256 + N_ROWS * 4;

    if (ws_size >= NEED) {
        char* p = (char*)d_ws;
        _Float16* zh = (_Float16*)p;            p += ZE * 2;
        _Float16* ch = (_Float16*)p;            p += CE * 2;
        float* esq   = (float*)p;               p += VOCAB * 4;
        float* pd1   = (float*)p;               p += P * 4;
        float* pd2   = (float*)p;               p += P * 4;
        int*   pi1   = (int*)p;                 p += P * 4;
        unsigned long long* rkey = (unsigned long long*)p;  p += (size_t)N_ROWS * 8;
        int*   flagcnt = (int*)p;               p += 256;
        int*   flaglist = (int*)p;

        prep_kernel<<<VOCAB / 4 + (int)(ZE / 4 / 256), 256, 0, stream>>>(
            z, cb, zh, ch, esq, cnt, rkey, flagcnt);
        mfma_dist_kernel<<<dim3(N_ROWS / BM, VSPLIT), 256, 0, stream>>>(
            zh, ch, esq, pd1, pi1, pd2);
        combine_kernel<<<N_ROWS / 4, 256, 0, stream>>>(
            pd1, pi1, pd2, cb, tokens, zq, cnt, flagcnt, flaglist);
        rescue6_kernel<<<VOCAB / 32, 256, 0, stream>>>(flagcnt, flaglist, z, cb, esq, rkey);
        rescue_write_kernel<<<32, 256, 0, stream>>>(flagcnt, flaglist, rkey, cb, tokens, zq, cnt);
    } else {
        float* esq   = (float*)d_ws;
        float* pdist = esq + VOCAB;
        int*   pidx  = (int*)(pdist + P);
        hipMemsetAsync(cnt, 0, VOCAB * sizeof(float), stream);
        esq_kernel<<<VOCAB / 4, 256, 0, stream>>>(cb, esq);
        fb_dist_kernel<<<dim3(N_ROWS / BM, VSPLIT), 256, 0, stream>>>(z, cb, esq, pdist, pidx);
        fb_combine_kernel<<<N_ROWS / 4, 256, 0, stream>>>(pdist, pidx, cb, tokens, zq, cnt);
    }
}

// Round 14
// 322.048 us; speedup vs baseline: 2.5107x; 1.4635x over previous
//
#include <hip/hip_runtime.h>
#include <math.h>

#define N_ROWS 16384
#define VOCAB  8192
#define EMB    256

// ---- MFMA path tiling ----
#define BM 128
#define BV 128
#define BK 64                      // halfs per staged cb K-chunk (2 MFMA k-steps)
#define VSPLIT 8                   // grid (128, 8)
#define VRANGE (VOCAB / VSPLIT)    // 1024
#define NVT    (VRANGE / BV)       // 8
#define TAU 0.15f                  // >= 2*max|dist err| over 1.3e8 pairs (fp16 inputs)

typedef _Float16 half8 __attribute__((ext_vector_type(8)));
typedef _Float16 half4 __attribute__((ext_vector_type(4)));
typedef float floatx4 __attribute__((ext_vector_type(4)));

// async global->LDS DMA, 16 B/lane; LDS dest = wave-uniform base + lane*16
__device__ __forceinline__ void load_lds16(const _Float16* g, _Float16* l) {
    __builtin_amdgcn_global_load_lds(
        (const __attribute__((address_space(1))) void*)g,
        (__attribute__((address_space(3))) void*)l, 16, 0, 0);
}

// ---------------------------------------------------------------------------
// PREP (1 dispatch: esq + fp16 convert + output/scratch init).
// ---------------------------------------------------------------------------
__global__ void prep_kernel(const float* __restrict__ z, const float* __restrict__ cb,
                            _Float16* __restrict__ zh, _Float16* __restrict__ ch,
                            float* __restrict__ esq, float* __restrict__ cnt,
                            unsigned long long* __restrict__ rkey,
                            int* __restrict__ flagcnt) {
    const int b = blockIdx.x, t = threadIdx.x;
    if (b < VOCAB / 4) {
        const int row  = b * 4 + (t >> 6);
        const int lane = t & 63;
        const float4 f = *(const float4*)(cb + (size_t)row * EMB + lane * 4);
        half4 h;
        h.x = (_Float16)f.x; h.y = (_Float16)f.y; h.z = (_Float16)f.z; h.w = (_Float16)f.w;
        *(half4*)(ch + (size_t)row * EMB + lane * 4) = h;
        float s = f.x * f.x + f.y * f.y + f.z * f.z + f.w * f.w;
        #pragma unroll
        for (int off = 32; off > 0; off >>= 1) s += __shfl_down(s, off, 64);
        if (lane == 0) esq[row] = s;
        if (t < 4) cnt[b * 4 + t] = 0.0f;
        if (t >= 8 && t < 16) rkey[b * 8 + (t - 8)] = ~0ull;
        if (b == 0 && t == 4) *flagcnt = 0;
    } else {
        const size_t idx4 = (size_t)(b - VOCAB / 4) * 256 + t;
        const float4 f = *(const float4*)(z + idx4 * 4);
        half4 h;
        h.x = (_Float16)f.x; h.y = (_Float16)f.y; h.z = (_Float16)f.z; h.w = (_Float16)f.w;
        *(half4*)(zh + idx4 * 4) = h;
    }
}

// ---------------------------------------------------------------------------
// MFMA dist kernel v9 (unchanged — counters finally due this round).
// z tile resident in LDS (swizzled slot = c ^ (r&31)); cb per-kt staging
// (v8 swizzle). acc init = -0.5*esq[col]; per-row ARGMAX of acc.
// ---------------------------------------------------------------------------
__global__ __launch_bounds__(256, 2)
void mfma_dist_kernel(const _Float16* __restrict__ zh, const _Float16* __restrict__ ch,
                      const float* __restrict__ esq,
                      float* __restrict__ pd1, int* __restrict__ pi1,
                      float* __restrict__ pd2) {
    __shared__ _Float16 zl[BM * 256];  // 64 KB, resident z tile (swizzled)
    __shared__ _Float16 cs[BV * BK];   // 16 KB, per-kt cb tile (v8 swizzle)
    float* sc_d1 = (float*)zl;         // end-phase alias (3 KB; z dead by then)
    float* sc_d2 = sc_d1 + BM * 2;
    int*   sc_i1 = (int*)(sc_d2 + BM * 2);

    const int row0  = blockIdx.x * BM;
    const int vbase = blockIdx.y * VRANGE;

    const int tid  = threadIdx.x;
    const int w    = tid >> 6;
    const int lane = tid & 63;
    const int lr   = lane & 15;
    const int quad = lane >> 4;
    const int mh   = (w >> 1) * 64;
    const int vh   = (w & 1) * 64;

    // ---- stage z ONCE ----
    {
        const int rl = lane >> 5;
        const int sc = lane & 31;
        #pragma unroll
        for (int i = 0; i < 16; ++i) {
            const int r = w * 32 + i * 2 + rl;
            const int c = sc ^ (i * 2 + rl);
            load_lds16(zh + (size_t)(row0 + r) * EMB + c * 8,
                       zl + (size_t)(w * 1024 + i * 64) * 8);
        }
    }

    int rowOffZ[4];
    #pragma unroll
    for (int i = 0; i < 4; ++i) rowOffZ[i] = (mh + i * 16 + lr) * 256;

    const int q7 = quad ^ (lr & 7);
    const int offA0 = q7 * 8;
    const int offA1 = (4 ^ q7) * 8;
    int rB[4];
    #pragma unroll
    for (int j = 0; j < 4; ++j) rB[j] = (vh + j * 16 + lr) * BK;

    const int schunk = (lane & 7) ^ (lane >> 3);

    float m1[16], m2[16]; int i1[16];
    #pragma unroll
    for (int t = 0; t < 16; ++t) { m1[t] = -INFINITY; m2[t] = -INFINITY; i1[t] = 0; }

    float ev[4];
    #pragma unroll
    for (int j = 0; j < 4; ++j) ev[j] = esq[vbase + vh + j * 16 + lr];

    __syncthreads();   // z DMA drained

    for (int vt = 0; vt < NVT; ++vt) {
        const int v0 = vbase + vt * BV;
        const _Float16* csrc = ch + (size_t)(v0 + w * 32 + (lane >> 3)) * EMB + schunk * 8;

        floatx4 acc[4][4];
        #pragma unroll
        for (int j = 0; j < 4; ++j) {
            const float e2 = -0.5f * ev[j];
            #pragma unroll
            for (int i = 0; i < 4; ++i) acc[i][j] = (floatx4)e2;
        }
        float evn[4];
        {
            const int vtn = (vt + 1 < NVT) ? vt + 1 : vt;
            #pragma unroll
            for (int j = 0; j < 4; ++j) evn[j] = esq[vbase + vtn * BV + vh + j * 16 + lr];
        }

        #pragma unroll 1
        for (int kt = 0; kt < EMB / BK; ++kt) {
            const int ko = kt * BK;
            #pragma unroll
            for (int q = 0; q < 4; ++q)
                load_lds16(csrc + (size_t)q * 8 * EMB + ko, &cs[w * 2048 + q * 512]);
            __syncthreads();

            #pragma unroll
            for (int s = 0; s < 2; ++s) {
                const int ks = kt * 2 + s;
                const int cE = (((ks << 2) | quad) ^ lr) << 3;
                const int cO = cE ^ 128;
                half8 a[4];
                a[0] = *(const half8*)&zl[rowOffZ[0] + cE];
                a[1] = *(const half8*)&zl[rowOffZ[1] + cO];
                a[2] = *(const half8*)&zl[rowOffZ[2] + cE];
                a[3] = *(const half8*)&zl[rowOffZ[3] + cO];
                const int off = s ? offA1 : offA0;
                #pragma unroll
                for (int j = 0; j < 4; ++j) {
                    const half8 b = *(const half8*)&cs[rB[j] + off];
                    #pragma unroll
                    for (int i = 0; i < 4; ++i)
                        acc[i][j] = __builtin_amdgcn_mfma_f32_16x16x32_f16(a[i], b, acc[i][j], 0, 0, 0);
                }
            }
            __syncthreads();
        }

        int vj[4];
        #pragma unroll
        for (int j = 0; j < 4; ++j) vj[j] = v0 + vh + j * 16 + lr;
        #pragma unroll
        for (int i = 0; i < 4; ++i) {
            #pragma unroll
            for (int reg = 0; reg < 4; ++reg) {
                const int t = i * 4 + reg;
                #pragma unroll
                for (int j = 0; j < 4; ++j) {
                    const float a = acc[i][j][reg];
                    m2[t] = fmaxf(m2[t], fminf(a, m1[t]));
                    i1[t] = (a > m1[t]) ? vj[j] : i1[t];
                    m1[t] = fmaxf(m1[t], a);
                }
            }
        }
        #pragma unroll
        for (int j = 0; j < 4; ++j) ev[j] = evn[j];
    }

    #pragma unroll
    for (int t = 0; t < 16; ++t) {
        float a1 = m1[t], a2 = m2[t]; int ii = i1[t];
        #pragma unroll
        for (int off = 1; off < 16; off <<= 1) {
            const float o1 = __shfl_xor(a1, off, 64);
            const int   oi = __shfl_xor(ii, off, 64);
            const float o2 = __shfl_xor(a2, off, 64);
            if (o1 > a1) { a2 = fmaxf(a1, o2); a1 = o1; ii = oi; }
            else         { a2 = fmaxf(a2, o1); }
        }
        m1[t] = a1; m2[t] = a2; i1[t] = ii;
    }
    if (lr == 0) {
        #pragma unroll
        for (int t = 0; t < 16; ++t) {
            const int r = mh + (t >> 2) * 16 + quad * 4 + (t & 3);
            sc_d1[r * 2 + (w & 1)] = m1[t];
            sc_d2[r * 2 + (w & 1)] = m2[t];
            sc_i1[r * 2 + (w & 1)] = i1[t];
        }
    }
    __syncthreads();
    if (tid < BM) {
        float a1 = sc_d1[tid * 2], a2 = sc_d2[tid * 2]; int ii = sc_i1[tid * 2];
        const float o1 = sc_d1[tid * 2 + 1], o2 = sc_d2[tid * 2 + 1];
        const int   oi = sc_i1[tid * 2 + 1];
        if (o1 > a1) { a2 = fmaxf(a1, o2); a1 = o1; ii = oi; }
        else         { a2 = fmaxf(a2, o1); }
        const size_t o = (size_t)blockIdx.y * N_ROWS + row0 + tid;
        pd1[o] = -2.0f * a1; pi1[o] = ii; pd2[o] = -2.0f * a2;
    }
}

// ---------------------------------------------------------------------------
// Combine: merge VSPLIT top-2 partials; margin >= TAU -> commit, else flag.
// ---------------------------------------------------------------------------
__global__ void combine_kernel(const float* __restrict__ pd1, const int* __restrict__ pi1,
                               const float* __restrict__ pd2,
                               const float* __restrict__ cb,
                               float* __restrict__ tokens, float* __restrict__ zq,
                               float* __restrict__ cnt,
                               int* __restrict__ flagcnt, int* __restrict__ flaglist) {
    const int wave = threadIdx.x >> 6;
    const int lane = threadIdx.x & 63;
    const int row  = blockIdx.x * 4 + wave;

    float d1 = INFINITY, d2 = INFINITY; int i1 = 0;
    #pragma unroll
    for (int s = 0; s < VSPLIT; ++s) {
        const size_t o = (size_t)s * N_ROWS + row;
        const float od1 = pd1[o], od2 = pd2[o]; const int oi1 = pi1[o];
        if (od1 < d1) { d2 = fminf(d1, od2); d1 = od1; i1 = oi1; }
        else          { d2 = fminf(d2, od1); }
    }
    if ((d2 - d1) < TAU) {
        if (lane == 0) {
            const int pos = atomicAdd(flagcnt, 1);
            flaglist[pos] = row;
        }
        return;   // rescue writes this row
    }
    if (lane == 0) {
        tokens[row] = (float)i1;
        atomicAdd(&cnt[i1], 1.0f);
    }
    const float4 v = *(const float4*)(cb + (size_t)i1 * EMB + lane * 4);
    *(float4*)(zq + (size_t)row * EMB + lane * 4) = v;
}

// ---------------------------------------------------------------------------
// Rescue v7: codebook-stationary (no-spill, round 13) + ROW-SPLIT grid
// (round 13's flaw: 256 blocks = 1/CU, rows serial -> 11% occupancy).
// Grid (256, 8): block (b, ry) stages codes [b*32, b*32+32) in LDS and
// processes row groups f0 = ry*4 + 32*it, 4 rows per iteration (4 indep
// dot chains). ~45 VGPRs; LDS 32 KB -> 4 blocks/CU resident.
// ---------------------------------------------------------------------------
__global__ __launch_bounds__(256, 4)
void rescue7_kernel(const int* __restrict__ flagcnt, const int* __restrict__ flaglist,
                    const float* __restrict__ z, const float* __restrict__ cb,
                    const float* __restrict__ esq,
                    unsigned long long* __restrict__ rkey) {
    __shared__ float cbs[32 * 256];   // 32 KB
    __shared__ float esqs[32];
    const int b    = blockIdx.x;      // codes [b*32, b*32+32)
    const int ry   = blockIdx.y;      // row split 0..7
    const int tid  = threadIdx.x;
    const int w    = tid >> 6;
    const int lane = tid & 63;
    const int v0   = b * 32;

    for (int i = tid; i < 32 * 64; i += 256)
        *(float4*)&cbs[i * 4] = *(const float4*)(cb + (size_t)v0 * EMB + i * 4);
    if (tid < 32) esqs[tid] = esq[v0 + tid];
    __syncthreads();

    const int n = *flagcnt;
    const int code = w * 8 + (lane >> 3);   // 0..31
    const int l0   = lane & 7;              // dim slice
    const float* crow = &cbs[code * EMB];
    const float ev = esqs[code];
    const int v = v0 + code;

    for (int f0 = ry * 4; f0 < n; f0 += 32) {
        int rws[4];
        #pragma unroll
        for (int r = 0; r < 4; ++r) {
            int f = f0 + r; if (f >= n) f = n - 1;   // dup pad: atomicMin idempotent
            rws[r] = flaglist[f];
        }
        float p[4] = {0.0f, 0.0f, 0.0f, 0.0f};
        #pragma unroll
        for (int kk = 0; kk < 8; ++kk) {
            const int idx = (l0 + 8 * kk) * 4;
            const float4 cv = *(const float4*)&crow[idx];
            #pragma unroll
            for (int r = 0; r < 4; ++r) {
                const float4 a4 = *(const float4*)(z + (size_t)rws[r] * EMB + idx);
                p[r] += a4.x * cv.x + a4.y * cv.y + a4.z * cv.z + a4.w * cv.w;
            }
        }
        #pragma unroll
        for (int off = 1; off < 8; off <<= 1) {
            #pragma unroll
            for (int r = 0; r < 4; ++r) p[r] += __shfl_xor(p[r], off, 64);
        }
        float d[4]; int bv[4];
        #pragma unroll
        for (int r = 0; r < 4; ++r) { d[r] = ev - 2.0f * p[r]; bv[r] = v; }
        #pragma unroll
        for (int off = 8; off < 64; off <<= 1) {
            #pragma unroll
            for (int r = 0; r < 4; ++r) {
                const float od = __shfl_xor(d[r], off, 64);
                const int   ov = __shfl_xor(bv[r], off, 64);
                if (od < d[r] || (od == d[r] && ov < bv[r])) { d[r] = od; bv[r] = ov; }
            }
        }
        if (lane == 0) {
            #pragma unroll
            for (int r = 0; r < 4; ++r) {
                unsigned int u = __float_as_uint(d[r]);
                u = (u & 0x80000000u) ? ~u : (u | 0x80000000u);
                atomicMin(rkey + rws[r], ((unsigned long long)u << 32) | (unsigned int)bv[r]);
            }
        }
    }
}

// ---------------------------------------------------------------------------
// Rescue writer: separate dispatch (kernel boundary = visibility ordering).
// ---------------------------------------------------------------------------
__global__ void rescue_write_kernel(const int* __restrict__ flagcnt,
                                    const int* __restrict__ flaglist,
                                    const unsigned long long* __restrict__ rkey,
                                    const float* __restrict__ cb,
                                    float* __restrict__ tokens, float* __restrict__ zq,
                                    float* __restrict__ cnt) {
    const int w    = threadIdx.x >> 6;
    const int lane = threadIdx.x & 63;
    const int n = *flagcnt;
    for (int f = blockIdx.x * 4 + w; f < n; f += gridDim.x * 4) {
        const int row = flaglist[f];
        const int v = (int)(unsigned int)(rkey[row] & 0xFFFFFFFFull);
        if (lane == 0) {
            tokens[row] = (float)v;
            atomicAdd(&cnt[v], 1.0f);
        }
        const float4 c4 = *(const float4*)(cb + (size_t)v * EMB + lane * 4);
        *(float4*)(zq + (size_t)row * EMB + lane * 4) = c4;
    }
}

// ===========================================================================
// Fallback (round-3 fp32 path) if ws is too small.
// ===========================================================================
__global__ void esq_kernel(const float* __restrict__ cb, float* __restrict__ esq) {
    const int wave = threadIdx.x >> 6;
    const int lane = threadIdx.x & 63;
    const int row  = blockIdx.x * 4 + wave;
    const float4 v = *(const float4*)(cb + (size_t)row * EMB + lane * 4);
    float s = v.x * v.x + v.y * v.y + v.z * v.z + v.w * v.w;
    #pragma unroll
    for (int off = 32; off > 0; off >>= 1) s += __shfl_down(s, off, 64);
    if (lane == 0) esq[row] = s;
}

#define FLSTR 36
__global__ __launch_bounds__(256, 2)
void fb_dist_kernel(const float* __restrict__ z, const float* __restrict__ cb,
                    const float* __restrict__ esq,
                    float* __restrict__ pdist, int* __restrict__ pidx) {
    __shared__ float zs[BM][FLSTR];
    __shared__ float es[BV][FLSTR];
    __shared__ float rdist[16][16];
    __shared__ int   ridx [16][16];
    const int row0 = blockIdx.x * BM, vbase = blockIdx.y * VRANGE;
    const int tid = threadIdx.x, wave = tid >> 6, lane = tid & 63;
    const int wly = (lane >> 3) & 7, wlx = lane & 7;
    const int wbase = (wave >> 1) * 64, cbase = (wave & 1) * 64;
    const int arow = wbase + wly, bcol = cbase + wlx;
    const int rowSlot = (wave >> 1) * 8 + wly, colSlot = (wave & 1) * 8 + wlx;
    const int sc4 = tid & 7, sr0 = tid >> 3;
    float best[8]; int bidx[8];
    #pragma unroll
    for (int i = 0; i < 8; ++i) { best[i] = INFINITY; bidx[i] = 0; }
    for (int vt = 0; vt < NVT; ++vt) {
        const int v0 = vbase + vt * BV;
        float acc[8][8];
        #pragma unroll
        for (int i = 0; i < 8; ++i)
            #pragma unroll
            for (int j = 0; j < 8; ++j) acc[i][j] = 0.0f;
        #pragma unroll 1
        for (int kt = 0; kt < EMB / 32; ++kt) {
            #pragma unroll
            for (int t = 0; t < 4; ++t) {
                const int r = sr0 + 32 * t;
                *(float4*)&zs[r][sc4 * 4] = *(const float4*)(z  + (size_t)(row0 + r) * EMB + kt * 32 + sc4 * 4);
                *(float4*)&es[r][sc4 * 4] = *(const float4*)(cb + (size_t)(v0 + r) * EMB + kt * 32 + sc4 * 4);
            }
            __syncthreads();
            #pragma unroll 1
            for (int k0 = 0; k0 < 8; ++k0) {
                const int kk = k0 * 4;
                float a[8][4];
                #pragma unroll
                for (int i = 0; i < 8; ++i) {
                    const float4 a4 = *(const float4*)&zs[arow + 8 * i][kk];
                    a[i][0] = a4.x; a[i][1] = a4.y; a[i][2] = a4.z; a[i][3] = a4.w;
                }
                #pragma unroll
                for (int j = 0; j < 8; ++j) {
                    const float4 b4 = *(const float4*)&es[bcol + 8 * j][kk];
                    #pragma unroll
                    for (int i = 0; i < 8; ++i) {
                        acc[i][j] += a[i][0] * b4.x; acc[i][j] += a[i][1] * b4.y;
                        acc[i][j] += a[i][2] * b4.z; acc[i][j] += a[i][3] * b4.w;
                    }
                }
            }
            __syncthreads();
        }
        #pragma unroll
        for (int j = 0; j < 8; ++j) {
            const int v = v0 + bcol + 8 * j;
            const float evv = esq[v];
            #pragma unroll
            for (int i = 0; i < 8; ++i) {
                const float d = evv - 2.0f * acc[i][j];
                if (d < best[i]) { best[i] = d; bidx[i] = v; }
            }
        }
    }
    for (int i = 0; i < 8; ++i) {
        rdist[rowSlot][colSlot] = best[i];
        ridx [rowSlot][colSlot] = bidx[i];
        __syncthreads();
        if (colSlot == 0) {
            float bd = rdist[rowSlot][0]; int bi = ridx[rowSlot][0];
            #pragma unroll
            for (int t = 1; t < 16; ++t) {
                const float d = rdist[rowSlot][t]; const int ii = ridx[rowSlot][t];
                if (d < bd || (d == bd && ii < bi)) { bd = d; bi = ii; }
            }
            const int row = row0 + wbase + 8 * i + wly;
            pdist[(size_t)blockIdx.y * N_ROWS + row] = bd;
            pidx [(size_t)blockIdx.y * N_ROWS + row] = bi;
        }
        __syncthreads();
    }
}

__global__ void fb_combine_kernel(const float* __restrict__ pdist, const int* __restrict__ pidx,
                                  const float* __restrict__ cb,
                                  float* __restrict__ tokens, float* __restrict__ zq,
                                  float* __restrict__ cnt) {
    const int wave = threadIdx.x >> 6, lane = threadIdx.x & 63;
    const int row = blockIdx.x * 4 + wave;
    float bd = INFINITY; int bi = 0;
    #pragma unroll
    for (int s = 0; s < VSPLIT; ++s) {
        const float d = pdist[(size_t)s * N_ROWS + row];
        const int ii  = pidx [(size_t)s * N_ROWS + row];
        if (d < bd || (d == bd && ii < bi)) { bd = d; bi = ii; }
    }
    if (lane == 0) { tokens[row] = (float)bi; atomicAdd(&cnt[bi], 1.0f); }
    const float4 v = *(const float4*)(cb + (size_t)bi * EMB + lane * 4);
    *(float4*)(zq + (size_t)row * EMB + lane * 4) = v;
}

// ---------------------------------------------------------------------------
// d_out: [0,N) tokens | [N, N+N*EMB) zq | +VOCAB ref_count
// ws: zh | ch | esq | pd1|pd2|pi1 | rkey | flagcnt | flaglist  ~= 13.8 MB
// 5 dispatches: prep -> mfma_dist -> combine -> rescue7 -> rescue_write
// ---------------------------------------------------------------------------
extern "C" void kernel_launch(void* const* d_in, const int* in_sizes, int n_in,
                              void* d_out, int out_size, void* d_ws, size_t ws_size,
                              hipStream_t stream) {
    const float* z  = (const float*)d_in[0];
    const float* cb = (const float*)d_in[1];

    float* out    = (float*)d_out;
    float* tokens = out;
    float* zq     = out + N_ROWS;
    float* cnt    = out + N_ROWS + (size_t)N_ROWS * EMB;

    const size_t ZE = (size_t)N_ROWS * EMB, CE = (size_t)VOCAB * EMB, P = (size_t)VSPLIT * N_ROWS;
    const size_t NEED = (ZE + CE) * sizeof(_Float16) + VOCAB * 4
                      + 3 * P * 4 + (size_t)N_ROWS * 8 + 256 + N_ROWS * 4;

    if (ws_size >= NEED) {
        char* p = (char*)d_ws;
        _Float16* zh = (_Float16*)p;            p += ZE * 2;
        _Float16* ch = (_Float16*)p;            p += CE * 2;
        float* esq   = (float*)p;               p += VOCAB * 4;
        float* pd1   = (float*)p;               p += P * 4;
        float* pd2   = (float*)p;               p += P * 4;
        int*   pi1   = (int*)p;                 p += P * 4;
        unsigned long long* rkey = (unsigned long long*)p;  p += (size_t)N_ROWS * 8;
        int*   flagcnt = (int*)p;               p += 256;
        int*   flaglist = (int*)p;

        prep_kernel<<<VOCAB / 4 + (int)(ZE / 4 / 256), 256, 0, stream>>>(
            z, cb, zh, ch, esq, cnt, rkey, flagcnt);
        mfma_dist_kernel<<<dim3(N_ROWS / BM, VSPLIT), 256, 0, stream>>>(
            zh, ch, esq, pd1, pi1, pd2);
        combine_kernel<<<N_ROWS / 4, 256, 0, stream>>>(
            pd1, pi1, pd2, cb, tokens, zq, cnt, flagcnt, flaglist);
        rescue7_kernel<<<dim3(VOCAB / 32, 8), 256, 0, stream>>>(
            flagcnt, flaglist, z, cb, esq, rkey);
        rescue_write_kernel<<<32, 256, 0, stream>>>(flagcnt, flaglist, rkey, cb, tokens, zq, cnt);
    } else {
        float* esq   = (float*)d_ws;
        float* pdist = esq + VOCAB;
        int*   pidx  = (int*)(pdist + P);
        hipMemsetAsync(cnt, 0, VOCAB * sizeof(float), stream);
        esq_kernel<<<VOCAB / 4, 256, 0, stream>>>(cb, esq);
        fb_dist_kernel<<<dim3(N_ROWS / BM, VSPLIT), 256, 0, stream>>>(z, cb, esq, pdist, pidx);
        fb_combine_kernel<<<N_ROWS / 4, 256, 0, stream>>>(pdist, pidx, cb, tokens, zq, cnt);
    }
}